// Round 2
// baseline (362.819 us; speedup 1.0000x reference)
//
#include <hip/hip_runtime.h>
#include <math.h>

#define MST 128
#define TLEN 131072
#define LOG2PI_F 1.8378770664093453f

#define CHUNKS 1024
#define CLEN (TLEN / CHUNKS)   /* 128 */
#define WARM 96

// ---------------- kernel 1: build Gamma rows (softmax with pinned diagonal) + u0 ----------------
__global__ void build_params(const float* __restrict__ tl,   // (M, M-1)
                             const float* __restrict__ il,   // (M,)
                             float* __restrict__ Gmat,       // (M, M)
                             float* __restrict__ u0) {       // (M,)
  __shared__ float red[MST];
  const int j = threadIdx.x;
  const int b = blockIdx.x;
  float lg;
  if (b < MST) {
    lg = (j == b) ? 0.0f : tl[b * (MST - 1) + (j > b ? j - 1 : j)];
  } else {
    lg = il[j];
  }
  float e = expf(lg);
  red[j] = e;
  __syncthreads();
  for (int s = MST / 2; s > 0; s >>= 1) {
    if (j < s) red[j] += red[j + s];
    __syncthreads();
  }
  float val = e / red[0];
  if (b < MST) Gmat[b * MST + j] = val;
  else u0[j] = val;
}

// ---------------- kernel 2: chunked scan, carry UNNORMALIZED w~, fold 1/S2 into next step ----------------
__global__ __launch_bounds__(128, 2)
void hmm_scan(const float* __restrict__ y,       // (T, 8)
              const float* __restrict__ means,   // (M, 8)
              const float* __restrict__ logsig,  // (M, 8)
              const float* __restrict__ Gmat,    // (M, M)
              const float* __restrict__ u0,      // (M,)
              float* __restrict__ outUt,         // (T, M)
              float* __restrict__ outF,          // (T,)
              float* __restrict__ outUtt) {      // (T, M)
  __shared__ __align__(16) float u_sh[MST];
  __shared__ float ps[2];
  const int j = threadIdx.x;
  const int b = blockIdx.x;
  const int t0 = b * CLEN;
  const int te = t0 + CLEN;
  int ts = t0 - WARM;
  if (ts < 0) ts = 0;

  // Gamma column j into registers (128 VGPRs)
  float col[MST];
#pragma unroll
  for (int i = 0; i < MST; ++i) col[i] = Gmat[i * MST + j];

  // per-state emission params in registers
  float mu[8], is[8];
  float cst = -4.0f * LOG2PI_F;
#pragma unroll
  for (int d = 0; d < 8; ++d) {
    mu[d] = means[j * 8 + d];
    float ls = logsig[j * 8 + d];
    is[d] = expf(-ls);
    cst -= ls;
  }

  // carried vector: exact u0 when chunk starts at t=0, else uniform + warmup.
  // u_sh holds the (possibly unnormalized) current vector; inv = 1/sum(u_sh).
  u_sh[j] = (ts == 0) ? u0[j] : (1.0f / MST);
  float inv = 1.0f;           // both inits sum to exactly 1
  __syncthreads();

  const float4* y4 = reinterpret_cast<const float4*>(y);
  float4 ya = y4[2 * ts];
  float4 yb = y4[2 * ts + 1];

  for (int t = ts; t < te; ++t) {
    // prefetch next observation (independent of recurrence)
    const int tn = (t + 1 < TLEN) ? t + 1 : t;
    float4 yna = y4[2 * tn];
    float4 ynb = y4[2 * tn + 1];

    // emission g[t][j] (independent of u_sh; overlaps the matvec)
    float q = 0.f, z;
    z = (ya.x - mu[0]) * is[0]; q = fmaf(z, z, q);
    z = (ya.y - mu[1]) * is[1]; q = fmaf(z, z, q);
    z = (ya.z - mu[2]) * is[2]; q = fmaf(z, z, q);
    z = (ya.w - mu[3]) * is[3]; q = fmaf(z, z, q);
    z = (yb.x - mu[4]) * is[4]; q = fmaf(z, z, q);
    z = (yb.y - mu[5]) * is[5]; q = fmaf(z, z, q);
    z = (yb.z - mu[6]) * is[6]; q = fmaf(z, z, q);
    z = (yb.w - mu[7]) * is[7]; q = fmaf(z, z, q);
    float g = __expf(fmaf(-0.5f, q, cst));

    // p~ = w~_{t-1} @ Gamma ; normalized predicted p = p~ * inv
    float p0 = 0.f, p1 = 0.f, p2 = 0.f, p3 = 0.f;
    const float4* u4 = reinterpret_cast<const float4*>(u_sh);
#pragma unroll
    for (int i = 0; i < MST / 4; ++i) {
      float4 uv = u4[i];
      p0 = fmaf(uv.x, col[4 * i + 0], p0);
      p1 = fmaf(uv.y, col[4 * i + 1], p1);
      p2 = fmaf(uv.z, col[4 * i + 2], p2);
      p3 = fmaf(uv.w, col[4 * i + 3], p3);
    }
    float p = ((p0 + p1) + (p2 + p3)) * inv;   // sums to 1 exactly (up to rounding)
    float w = p * g;                           // w~_t, sum = f_t

    __syncthreads();          // all lanes done reading u_sh
    u_sh[j] = w;              // store unnormalized — no wait on the reduction!

    // block-wide sum S2 = f_t : wave butterfly + cross-wave via LDS
    float s = w;
    s += __shfl_xor(s, 1);
    s += __shfl_xor(s, 2);
    s += __shfl_xor(s, 4);
    s += __shfl_xor(s, 8);
    s += __shfl_xor(s, 16);
    s += __shfl_xor(s, 32);
    if ((j & 63) == 0) ps[j >> 6] = s;
    __syncthreads();          // u_sh + ps visible
    float S2 = ps[0] + ps[1];
    float invNew = __builtin_amdgcn_rcpf(S2);

    if (t >= t0) {
      outUt[(size_t)t * MST + j]  = w * invNew;  // filtered (rcp error cancels in ratio)
      outUtt[(size_t)t * MST + j] = p;           // predicted
      if (j == 0) outF[t] = S2;                  // per-step likelihood
    }

    inv = invNew;
    ya = yna; yb = ynb;
  }
}

extern "C" void kernel_launch(void* const* d_in, const int* in_sizes, int n_in,
                              void* d_out, int out_size, void* d_ws, size_t ws_size,
                              hipStream_t stream) {
  const float* y  = (const float*)d_in[0];
  const float* tl = (const float*)d_in[1];
  const float* il = (const float*)d_in[2];
  const float* mu = (const float*)d_in[3];
  const float* ls = (const float*)d_in[4];

  float* Gmat = (float*)d_ws;              // 128*128 floats
  float* u0   = Gmat + MST * MST;          // 128 floats

  float* outUt  = (float*)d_out;
  float* outF   = outUt + (size_t)TLEN * MST;
  float* outUtt = outF + TLEN;

  build_params<<<MST + 1, MST, 0, stream>>>(tl, il, Gmat, u0);
  hmm_scan<<<CHUNKS, MST, 0, stream>>>(y, mu, ls, Gmat, u0,
                                       outUt, outF, outUtt);
}

// Round 3
// 346.520 us; speedup vs baseline: 1.0470x; 1.0470x over previous
//
#include <hip/hip_runtime.h>
#include <math.h>

#define MST   128
#define DOBS  8
#define TLEN  131072
#define LOG2PI_F 1.8378770664093453f

#define CLEN   32
#define CHUNKS (TLEN / CLEN)          /* 4096 */
#define BCH    16                     /* chains (slots) per block */
#define NBLK   (CHUNKS / BCH)         /* 256 */
#define WARM   96
#define SSTAG  8
#define NSPAN  (SSTAG * (BCH - 1) + WARM + CLEN)   /* 248 */

#define FBYTES   ((unsigned)TLEN * MST * 4u)             /* 67108864: f base   */
#define UTTBYTES (FBYTES + (unsigned)TLEN * 4u)          /* 67633152: Utt base */
#define OUTBYTES (UTTBYTES + (unsigned)TLEN * MST * 4u)  /* 134742016          */
#define VOOB 0xE0000000u

typedef __attribute__((ext_vector_type(8))) short v8s;   /* bf16x8 MFMA frag */
typedef __attribute__((ext_vector_type(4))) float v4f;
typedef __attribute__((ext_vector_type(4))) unsigned int v4u;

__device__ __forceinline__ unsigned short f2bf(float x) {
  unsigned int b = __builtin_bit_cast(unsigned int, x);
  unsigned int r = b + 0x7FFFu + ((b >> 16) & 1u);
  return (unsigned short)(r >> 16);
}
__device__ __forceinline__ float bf2f(unsigned short h) {
  unsigned int b = ((unsigned int)h) << 16;
  return __builtin_bit_cast(float, b);
}
__device__ __forceinline__ v4u make_rsrc(const void* p, unsigned int bytes) {
  unsigned long long a = (unsigned long long)p;
  v4u r;
  r.x = (unsigned int)a;
  r.y = (unsigned int)(a >> 32) & 0xFFFFu;
  r.z = bytes;
  r.w = 0x00020000u;
  return r;
}
/* buffer store with HW bounds check: voffset >= num_records is silently dropped */
__device__ __forceinline__ void bstore(float v, unsigned int voff, v4u rs) {
  asm volatile("buffer_store_dword %0, %1, %2, 0 offen"
               :: "v"(v), "v"(voff), "s"(rs));
}

/* ---------- kernel 1: Gamma (bf16 hi/lo, transposed) + u0 + emission consts ---------- */
__global__ void build_params(const float* __restrict__ tl,
                             const float* __restrict__ il,
                             const float* __restrict__ ls,
                             unsigned short* __restrict__ GhiT,
                             unsigned short* __restrict__ GloT,
                             float* __restrict__ u0,
                             float* __restrict__ isb,
                             float* __restrict__ cstb) {
  __shared__ float red[MST];
  const int j = threadIdx.x;
  const int b = blockIdx.x;
  float lg;
  if (b < MST) lg = (j == b) ? 0.0f : tl[b * (MST - 1) + (j > b ? j - 1 : j)];
  else         lg = il[j];
  float e = __expf(lg);
  red[j] = e;
  __syncthreads();
  for (int s = MST / 2; s > 0; s >>= 1) {
    if (j < s) red[j] += red[j + s];
    __syncthreads();
  }
  float val = e / red[0];
  if (b < MST) {
    unsigned short h = f2bf(val);
    GhiT[j * MST + b] = h;                       /* Gamma^T: [n=dest][k=src] */
    GloT[j * MST + b] = f2bf(val - bf2f(h));
  } else {
    u0[j] = val;
    float c = -((float)DOBS * 0.5f) * LOG2PI_F;
#pragma unroll
    for (int d = 0; d < DOBS; ++d) {
      float l = ls[j * DOBS + d];
      isb[j * DOBS + d] = __expf(-l);
      c -= l;
    }
    cstb[j] = c;
  }
}

/* ---------- kernel 2: emission densities g[t][j] (fully parallel) ---------- */
__global__ void emis_kernel(const float* __restrict__ y,
                            const float* __restrict__ mu,
                            const float* __restrict__ isb,
                            const float* __restrict__ cstb,
                            float* __restrict__ g) {
  const int t = blockIdx.x;
  const int j = threadIdx.x;
  __shared__ float ysh[DOBS];
  if (j < DOBS) ysh[j] = y[t * DOBS + j];
  __syncthreads();
  float q = 0.0f;
#pragma unroll
  for (int d = 0; d < DOBS; ++d) {
    float z = (ysh[d] - mu[j * DOBS + d]) * isb[j * DOBS + d];
    q = fmaf(z, z, q);
  }
  g[(size_t)t * MST + j] = __expf(fmaf(-0.5f, q, cstb[j]));
}

/* ---------- kernel 3: batched MFMA scan, 16 staggered chains per block ---------- */
__global__ __launch_bounds__(256, 1)
void hmm_scan(const float* __restrict__ g,
              const unsigned short* __restrict__ GhiT,
              const unsigned short* __restrict__ GloT,
              const float* __restrict__ u0,
              float* __restrict__ outbase) {
  __shared__ __align__(16) unsigned short Xh[BCH * MST];  /* [chain][state] bf16, xor-swz */
  __shared__ __align__(16) unsigned short Xl[BCH * MST];
  __shared__ __align__(16) float redp[BCH * 4];           /* [row][wave] partial rowsums */

  const int tid = threadIdx.x;
  const int wv  = tid >> 6;
  const int ln  = tid & 63;
  const int grp = ln >> 4;
  const int li  = ln & 15;
  const int b   = blockIdx.x;
  const int r0  = grp * 4;
  const int col0 = wv * 32 + li;
  const int col1 = col0 + 16;

  const v4u rs = make_rsrc(outbase, OUTBYTES);

  /* Gamma B-fragments in registers (hi+lo): 16 frags x 4 VGPR */
  v8s Bh0[4], Bh1[4], Bl0[4], Bl1[4];
#pragma unroll
  for (int kt = 0; kt < 4; ++kt) {
    const int k = kt * 32 + grp * 8;
    Bh0[kt] = *(const v8s*)(GhiT + col0 * MST + k);
    Bh1[kt] = *(const v8s*)(GhiT + col1 * MST + k);
    Bl0[kt] = *(const v8s*)(GloT + col0 * MST + k);
    Bl1[kt] = *(const v8s*)(GloT + col1 * MST + k);
  }

  /* per-row (slot) constants */
  int t00[4], ts[4], tcur[4];
  float init0[4], init1[4];
  const float u0c0 = u0[col0], u0c1 = u0[col1];
#pragma unroll
  for (int q = 0; q < 4; ++q) {
    const int r = r0 + q;
    t00[q] = (b * BCH + r) * CLEN;
    int tsq = t00[q] - WARM; if (tsq < 0) tsq = 0;
    ts[q] = tsq;
    tcur[q] = t00[q] - WARM - SSTAG * r;       /* staggered start */
    const bool fromU0 = (tsq == 0);            /* early chunks: exact u0 init */
    init0[q] = fromU0 ? u0c0 : (1.0f / MST);
    init1[q] = fromU0 ? u0c1 : (1.0f / MST);
  }

  /* prologue: W̃ = init, publish X + red, prefetch g */
  float wp0[4], wp1[4];
  int tp[4];
  float gc0[4], gc1[4];
#pragma unroll
  for (int q = 0; q < 4; ++q) { wp0[q] = init0[q]; wp1[q] = init1[q]; tp[q] = tcur[q] - 1; }
#pragma unroll
  for (int q = 0; q < 4; ++q) {
    float s = wp0[q] + wp1[q];
    s += __shfl_xor(s, 1); s += __shfl_xor(s, 2);
    s += __shfl_xor(s, 4); s += __shfl_xor(s, 8);
    const int r = r0 + q;
    const unsigned off0 = ((unsigned)(r * 256 + col0 * 2)) ^ (unsigned)((r & 7) << 4);
    const unsigned off1 = ((unsigned)(r * 256 + col1 * 2)) ^ (unsigned)((r & 7) << 4);
    const unsigned short h0 = f2bf(wp0[q]);
    const unsigned short h1 = f2bf(wp1[q]);
    *(unsigned short*)((char*)Xh + off0) = h0;
    *(unsigned short*)((char*)Xh + off1) = h1;
    *(unsigned short*)((char*)Xl + off0) = f2bf(wp0[q] - bf2f(h0));
    *(unsigned short*)((char*)Xl + off1) = f2bf(wp1[q] - bf2f(h1));
    if (li == 0) redp[r * 4 + wv] = s;
  }
#pragma unroll
  for (int q = 0; q < 4; ++q) {
    int tm = tcur[q]; tm = tm < 0 ? 0 : (tm >= TLEN ? TLEN - 1 : tm);
    gc0[q] = g[(size_t)tm * MST + col0];
    gc1[q] = g[(size_t)tm * MST + col1];
  }
  __syncthreads();

  for (int n = 0; n <= NSPAN; ++n) {
    /* 1. A-fragments of W̃_{n-1} from LDS (swizzled, conflict-free b128) */
    v8s Ah[4], Al[4];
#pragma unroll
    for (int kt = 0; kt < 4; ++kt) {
      const unsigned off = ((unsigned)(li * 256 + kt * 64 + grp * 16)) ^ (unsigned)((li & 7) << 4);
      Ah[kt] = *(const v8s*)((const char*)Xh + off);
      Al[kt] = *(const v8s*)((const char*)Xl + off);
    }
    /* 2. rowsums of W̃_{n-1} -> S (= f at tp), inv */
    float S[4], inv[4];
#pragma unroll
    for (int q = 0; q < 4; ++q) {
      v4f rp = *(const v4f*)(redp + (r0 + q) * 4);
      S[q] = (rp.x + rp.y) + (rp.z + rp.w);
      inv[q] = __builtin_amdgcn_rcpf(S[q]);
    }
    /* 3. prefetch next g */
    float gn0[4], gn1[4];
#pragma unroll
    for (int q = 0; q < 4; ++q) {
      int tm = tcur[q] + 1; tm = tm < 0 ? 0 : (tm >= TLEN ? TLEN - 1 : tm);
      gn0[q] = g[(size_t)tm * MST + col0];
      gn1[q] = g[(size_t)tm * MST + col1];
    }
    /* 4. lagged stores: Ut and f at tp (OOB-dropped when inactive) */
#pragma unroll
    for (int q = 0; q < 4; ++q) {
      const bool act = (tp[q] >= t00[q]) & (tp[q] < t00[q] + CLEN);
      const unsigned tb = (unsigned)tp[q] * 512u;
      bstore(wp0[q] * inv[q], act ? tb + (unsigned)col0 * 4u : VOOB, rs);
      bstore(wp1[q] * inv[q], act ? tb + (unsigned)col1 * 4u : VOOB, rs);
      bstore(S[q], (act && wv == 0 && li == 0) ? FBYTES + (unsigned)tp[q] * 4u : VOOB, rs);
    }
    /* 5. P̃ = W̃ @ Γ, 3-term bf16-compensated */
    v4f C0 = {0.f, 0.f, 0.f, 0.f}, C1 = {0.f, 0.f, 0.f, 0.f};
#pragma unroll
    for (int kt = 0; kt < 4; ++kt) {
      C0 = __builtin_amdgcn_mfma_f32_16x16x32_bf16(Ah[kt], Bh0[kt], C0, 0, 0, 0);
      C1 = __builtin_amdgcn_mfma_f32_16x16x32_bf16(Ah[kt], Bh1[kt], C1, 0, 0, 0);
      C0 = __builtin_amdgcn_mfma_f32_16x16x32_bf16(Al[kt], Bh0[kt], C0, 0, 0, 0);
      C1 = __builtin_amdgcn_mfma_f32_16x16x32_bf16(Al[kt], Bh1[kt], C1, 0, 0, 0);
      C0 = __builtin_amdgcn_mfma_f32_16x16x32_bf16(Ah[kt], Bl0[kt], C0, 0, 0, 0);
      C1 = __builtin_amdgcn_mfma_f32_16x16x32_bf16(Ah[kt], Bl1[kt], C1, 0, 0, 0);
    }
    /* 6. p (normalized prediction) -> Utt store; w = p*g with hold-gating */
    float w0[4], w1[4];
#pragma unroll
    for (int q = 0; q < 4; ++q) {
      const float p0 = C0[q] * inv[q];
      const float p1 = C1[q] * inv[q];
      const bool act = (tcur[q] >= t00[q]) & (tcur[q] < t00[q] + CLEN);
      const unsigned tb = UTTBYTES + (unsigned)tcur[q] * 512u;
      bstore(p0, act ? tb + (unsigned)col0 * 4u : VOOB, rs);
      bstore(p1, act ? tb + (unsigned)col1 * 4u : VOOB, rs);
      const float a0 = p0 * gc0[q];
      const float a1 = p1 * gc1[q];
      const bool hold = tcur[q] < ts[q];
      w0[q] = hold ? init0[q] : a0;
      w1[q] = hold ? init1[q] : a1;
    }
    /* 7. partial rowsums over this wave's 32 cols (result used NEXT step) */
    float s4[4];
#pragma unroll
    for (int q = 0; q < 4; ++q) {
      float s = w0[q] + w1[q];
      s += __shfl_xor(s, 1); s += __shfl_xor(s, 2);
      s += __shfl_xor(s, 4); s += __shfl_xor(s, 8);
      s4[q] = s;
    }
    /* 8. publish W̃_n (bf16 hi/lo) + red partials */
    __syncthreads();
#pragma unroll
    for (int q = 0; q < 4; ++q) {
      const int r = r0 + q;
      const unsigned off0 = ((unsigned)(r * 256 + col0 * 2)) ^ (unsigned)((r & 7) << 4);
      const unsigned off1 = ((unsigned)(r * 256 + col1 * 2)) ^ (unsigned)((r & 7) << 4);
      const unsigned short h0 = f2bf(w0[q]);
      const unsigned short h1 = f2bf(w1[q]);
      *(unsigned short*)((char*)Xh + off0) = h0;
      *(unsigned short*)((char*)Xh + off1) = h1;
      *(unsigned short*)((char*)Xl + off0) = f2bf(w0[q] - bf2f(h0));
      *(unsigned short*)((char*)Xl + off1) = f2bf(w1[q] - bf2f(h1));
    }
    if (li == 0) {
#pragma unroll
      for (int q = 0; q < 4; ++q) redp[(r0 + q) * 4 + wv] = s4[q];
    }
    __syncthreads();
    /* 9. rotate */
#pragma unroll
    for (int q = 0; q < 4; ++q) {
      wp0[q] = w0[q]; wp1[q] = w1[q];
      tp[q] = tcur[q]; tcur[q] += 1;
      gc0[q] = gn0[q]; gc1[q] = gn1[q];
    }
  }
}

extern "C" void kernel_launch(void* const* d_in, const int* in_sizes, int n_in,
                              void* d_out, int out_size, void* d_ws, size_t ws_size,
                              hipStream_t stream) {
  const float* y  = (const float*)d_in[0];
  const float* tl = (const float*)d_in[1];
  const float* il = (const float*)d_in[2];
  const float* mu = (const float*)d_in[3];
  const float* ls = (const float*)d_in[4];

  /* workspace layout: g (67MB) | u0 | GhiT | GloT | isb | cstb  (~67.2MB total) */
  float* wsf = (float*)d_ws;
  float* g   = wsf;
  float* u0  = wsf + (size_t)TLEN * MST;
  unsigned short* GhiT = (unsigned short*)(u0 + MST);
  unsigned short* GloT = GhiT + MST * MST;
  float* isb  = (float*)(GloT + MST * MST);
  float* cstb = isb + MST * DOBS;

  build_params<<<MST + 1, MST, 0, stream>>>(tl, il, ls, GhiT, GloT, u0, isb, cstb);
  emis_kernel<<<TLEN, MST, 0, stream>>>(y, mu, isb, cstb, g);
  hmm_scan<<<NBLK, 256, 0, stream>>>(g, GhiT, GloT, u0, (float*)d_out);
}

// Round 4
// 282.145 us; speedup vs baseline: 1.2859x; 1.2282x over previous
//
#include <hip/hip_runtime.h>
#include <math.h>

#define MST   128
#define DOBS  8
#define TLEN  131072
#define LOG2PI_F 1.8378770664093453f

#define CLEN   32
#define CHUNKS (TLEN / CLEN)          /* 4096 */
#define BCH    16                     /* chains (rows) per block */
#define NBLK   (CHUNKS / BCH)         /* 256 */
#define WARM   96
#define SSTAG  8
#define NSPAN  (SSTAG * (BCH - 1) + WARM + CLEN)   /* 248 */
#define EROWS  16

#define XBUF   (BCH * MST * 2)        /* 4096 bytes per X buffer */

#define FBYTES   ((unsigned)TLEN * MST * 4u)             /* f base   */
#define UTTBYTES (FBYTES + (unsigned)TLEN * 4u)          /* Utt base */
#define OUTBYTES (UTTBYTES + (unsigned)TLEN * MST * 4u)
#define VOOB 0xE0000000u

typedef __attribute__((ext_vector_type(8))) short v8s;
typedef __attribute__((ext_vector_type(4))) float v4f;
typedef __attribute__((ext_vector_type(4))) unsigned int v4u;

__device__ __forceinline__ unsigned short f2bf_rne(float x) {
  unsigned int b = __builtin_bit_cast(unsigned int, x);
  unsigned int r = b + 0x7FFFu + ((b >> 16) & 1u);
  return (unsigned short)(r >> 16);
}
__device__ __forceinline__ float bf2f(unsigned short h) {
  unsigned int b = ((unsigned int)h) << 16;
  return __builtin_bit_cast(float, b);
}
__device__ __forceinline__ v4u make_rsrc(const void* p, unsigned int bytes) {
  unsigned long long a = (unsigned long long)p;
  v4u r;
  r.x = (unsigned int)a;
  r.y = (unsigned int)(a >> 32) & 0xFFFFu;
  r.z = bytes;
  r.w = 0x00020000u;
  return r;
}
__device__ __forceinline__ void bstore(float v, unsigned int voff, v4u rs) {
  asm volatile("buffer_store_dword %0, %1, %2, 0 offen"
               :: "v"(v), "v"(voff), "s"(rs));
}
/* LDS-only barrier: order LDS, do NOT drain vmcnt (buffer stores / global loads) */
__device__ __forceinline__ void ldsbar() {
  asm volatile("s_waitcnt lgkmcnt(0)" ::: "memory");
  __builtin_amdgcn_sched_barrier(0);
  __builtin_amdgcn_s_barrier();
  __builtin_amdgcn_sched_barrier(0);
}

/* ---------- kernel 1: Gamma (bf16 hi/lo, transposed) + u0 + emission consts ---------- */
__global__ void build_params(const float* __restrict__ tl,
                             const float* __restrict__ il,
                             const float* __restrict__ ls,
                             unsigned short* __restrict__ GhiT,
                             unsigned short* __restrict__ GloT,
                             float* __restrict__ u0,
                             float* __restrict__ isb,
                             float* __restrict__ cstb) {
  __shared__ float red[MST];
  const int j = threadIdx.x;
  const int b = blockIdx.x;
  float lg;
  if (b < MST) lg = (j == b) ? 0.0f : tl[b * (MST - 1) + (j > b ? j - 1 : j)];
  else         lg = il[j];
  float e = __expf(lg);
  red[j] = e;
  __syncthreads();
  for (int s = MST / 2; s > 0; s >>= 1) {
    if (j < s) red[j] += red[j + s];
    __syncthreads();
  }
  float val = e / red[0];
  if (b < MST) {
    unsigned short h = f2bf_rne(val);
    GhiT[j * MST + b] = h;                       /* Gamma^T: [dest][src] */
    GloT[j * MST + b] = f2bf_rne(val - bf2f(h));
  } else {
    u0[j] = val;
    float c = -((float)DOBS * 0.5f) * LOG2PI_F;
#pragma unroll
    for (int d = 0; d < DOBS; ++d) {
      float l = ls[j * DOBS + d];
      isb[j * DOBS + d] = __expf(-l);
      c -= l;
    }
    cstb[j] = c;
  }
}

/* ---------- kernel 2: emission densities, 16 rows per block ---------- */
__global__ void emis_kernel(const float* __restrict__ y,
                            const float* __restrict__ mu,
                            const float* __restrict__ isb,
                            const float* __restrict__ cstb,
                            float* __restrict__ g) {
  const int j  = threadIdx.x;
  const int tb = blockIdx.x * EROWS;
  __shared__ float ysh[EROWS * DOBS];
  ysh[j] = y[(unsigned)tb * DOBS + j];
  __syncthreads();
  float m[DOBS], is[DOBS];
  float cst = cstb[j];
#pragma unroll
  for (int d = 0; d < DOBS; ++d) { m[d] = mu[j * DOBS + d]; is[d] = isb[j * DOBS + d]; }
#pragma unroll
  for (int r = 0; r < EROWS; ++r) {
    float q = 0.0f;
#pragma unroll
    for (int d = 0; d < DOBS; ++d) {
      float z = (ysh[r * DOBS + d] - m[d]) * is[d];
      q = fmaf(z, z, q);
    }
    g[(unsigned)(tb + r) * MST + j] = __expf(fmaf(-0.5f, q, cst));
  }
}

/* ---------- kernel 3: batched MFMA scan, double-buffered X, 1 LDS barrier/step ---------- */
__global__ __launch_bounds__(256, 1)
void hmm_scan(const float* __restrict__ g,
              const unsigned short* __restrict__ GhiT,
              const unsigned short* __restrict__ GloT,
              const float* __restrict__ u0,
              float* __restrict__ outbase) {
  __shared__ __align__(16) unsigned short Xh[2][BCH * MST];
  __shared__ __align__(16) unsigned short Xl[2][BCH * MST];
  char* xh = (char*)&Xh[0][0];
  char* xl = (char*)&Xl[0][0];

  const int tid = threadIdx.x;
  const int wv  = tid >> 6;
  const int ln  = tid & 63;
  const int grp = ln >> 4;
  const int li  = ln & 15;
  const int b   = blockIdx.x;
  const int r0  = grp * 4;
  const int col0 = wv * 32 + li;
  const int col1 = col0 + 16;

  const v4u rs = make_rsrc(outbase, OUTBYTES);

  /* Gamma B-fragments (hi+lo) */
  v8s Bh0[4], Bh1[4], Bl0[4], Bl1[4];
#pragma unroll
  for (int kt = 0; kt < 4; ++kt) {
    const int k = kt * 32 + grp * 8;
    Bh0[kt] = *(const v8s*)(GhiT + col0 * MST + k);
    Bh1[kt] = *(const v8s*)(GhiT + col1 * MST + k);
    Bl0[kt] = *(const v8s*)(GloT + col0 * MST + k);
    Bl1[kt] = *(const v8s*)(GloT + col1 * MST + k);
  }
  const short bf1 = (short)0x3F80;   /* bf16 1.0 */
  const v8s ONE = {bf1, bf1, bf1, bf1, bf1, bf1, bf1, bf1};

  /* per-row constants */
  int t00[4], ts[4], tend[4], tcur[4];
  float init0[4], init1[4];
  const float u0c0 = u0[col0], u0c1 = u0[col1];
#pragma unroll
  for (int q = 0; q < 4; ++q) {
    const int r = r0 + q;
    t00[q] = (b * BCH + r) * CLEN;
    int tsq = t00[q] - WARM; if (tsq < 0) tsq = 0;
    ts[q] = tsq;
    tend[q] = t00[q] + CLEN;
    tcur[q] = t00[q] - WARM - SSTAG * r;
    const bool fromU0 = (tsq == 0);
    init0[q] = fromU0 ? u0c0 : (1.0f / MST);
    init1[q] = fromU0 ? u0c1 : (1.0f / MST);
  }

  /* prologue: publish X[0] = init, prefetch g */
  float wp0[4], wp1[4], gc0[4], gc1[4];
#pragma unroll
  for (int q = 0; q < 4; ++q) {
    wp0[q] = init0[q]; wp1[q] = init1[q];
    const int r = r0 + q;
    const unsigned sw = (unsigned)((r & 7) << 4);
    const unsigned off0 = ((unsigned)(r * 256 + col0 * 2)) ^ sw;
    const unsigned off1 = ((unsigned)(r * 256 + col1 * 2)) ^ sw;
    unsigned b0 = __builtin_bit_cast(unsigned, wp0[q]);
    unsigned b1 = __builtin_bit_cast(unsigned, wp1[q]);
    float hf0 = __builtin_bit_cast(float, b0 & 0xFFFF0000u);
    float hf1 = __builtin_bit_cast(float, b1 & 0xFFFF0000u);
    *(unsigned short*)(xh + off0) = (unsigned short)(b0 >> 16);
    *(unsigned short*)(xh + off1) = (unsigned short)(b1 >> 16);
    *(unsigned short*)(xl + off0) = (unsigned short)(__builtin_bit_cast(unsigned, wp0[q] - hf0) >> 16);
    *(unsigned short*)(xl + off1) = (unsigned short)(__builtin_bit_cast(unsigned, wp1[q] - hf1) >> 16);
    unsigned tm = (unsigned)tcur[q]; tm = tm < (TLEN - 1u) ? tm : (TLEN - 1u);
    gc0[q] = g[tm * MST + col0];
    gc1[q] = g[tm * MST + col1];
  }
  ldsbar();

  for (int n = 0; n <= NSPAN; ++n) {
    const unsigned rbase = (unsigned)(n & 1) * XBUF;
    const unsigned wbase = rbase ^ XBUF;

    /* 1. A-fragments of W̃ from X[n&1] */
    v8s Ah[4], Al[4];
#pragma unroll
    for (int kt = 0; kt < 4; ++kt) {
      const unsigned off = rbase + (((unsigned)(li * 256 + kt * 64 + grp * 16)) ^ ((unsigned)((li & 7) << 4)));
      Ah[kt] = *(const v8s*)(xh + off);
      Al[kt] = *(const v8s*)(xl + off);
    }

    /* 2. row sums via MFMA against ones (replaces shfl reduce) */
    v4f Csa = {0.f,0.f,0.f,0.f}, Csb = {0.f,0.f,0.f,0.f};
#pragma unroll
    for (int kt = 0; kt < 4; ++kt) {
      Csa = __builtin_amdgcn_mfma_f32_16x16x32_bf16(Ah[kt], ONE, Csa, 0, 0, 0);
      Csb = __builtin_amdgcn_mfma_f32_16x16x32_bf16(Al[kt], ONE, Csb, 0, 0, 0);
    }

    /* 3. P̃ = W̃ @ Γ, 3-term compensated, split accumulators (depth 4) */
    v4f C0a = {0.f,0.f,0.f,0.f}, C0b = {0.f,0.f,0.f,0.f}, C0c = {0.f,0.f,0.f,0.f};
    v4f C1a = {0.f,0.f,0.f,0.f}, C1b = {0.f,0.f,0.f,0.f}, C1c = {0.f,0.f,0.f,0.f};
#pragma unroll
    for (int kt = 0; kt < 4; ++kt) {
      C0a = __builtin_amdgcn_mfma_f32_16x16x32_bf16(Ah[kt], Bh0[kt], C0a, 0, 0, 0);
      C1a = __builtin_amdgcn_mfma_f32_16x16x32_bf16(Ah[kt], Bh1[kt], C1a, 0, 0, 0);
      C0b = __builtin_amdgcn_mfma_f32_16x16x32_bf16(Al[kt], Bh0[kt], C0b, 0, 0, 0);
      C1b = __builtin_amdgcn_mfma_f32_16x16x32_bf16(Al[kt], Bh1[kt], C1b, 0, 0, 0);
      C0c = __builtin_amdgcn_mfma_f32_16x16x32_bf16(Ah[kt], Bl0[kt], C0c, 0, 0, 0);
      C1c = __builtin_amdgcn_mfma_f32_16x16x32_bf16(Ah[kt], Bl1[kt], C1c, 0, 0, 0);
    }

    /* 4. prefetch next g (counted vmcnt handled by compiler; never drained) */
    float gn0[4], gn1[4];
#pragma unroll
    for (int q = 0; q < 4; ++q) {
      unsigned tm = (unsigned)(tcur[q] + 1); tm = tm < (TLEN - 1u) ? tm : (TLEN - 1u);
      gn0[q] = g[tm * MST + col0];
      gn1[q] = g[tm * MST + col1];
    }

    /* 5. S, inv, p */
    float S[4], inv[4], p0[4], p1[4];
#pragma unroll
    for (int q = 0; q < 4; ++q) {
      S[q] = Csa[q] + Csb[q];
      inv[q] = __builtin_amdgcn_rcpf(S[q]);
      p0[q] = ((C0a[q] + C0b[q]) + C0c[q]) * inv[q];
      p1[q] = ((C1a[q] + C1b[q]) + C1c[q]) * inv[q];
    }

    /* 6. stores (wave-uniform guard; inactive gated via OOB drop) */
    if (n >= WARM) {
#pragma unroll
      for (int q = 0; q < 4; ++q) {
        const bool act  = (unsigned)(tcur[q] - t00[q]) < (unsigned)CLEN;
        const bool actp = (unsigned)(tcur[q] - 1 - t00[q]) < (unsigned)CLEN;
        const unsigned tb = (unsigned)tcur[q] * 512u;
        bstore(p0[q], act ? UTTBYTES + tb + (unsigned)col0 * 4u : VOOB, rs);
        bstore(p1[q], act ? UTTBYTES + tb + (unsigned)col1 * 4u : VOOB, rs);
        const unsigned tbp = tb - 512u;
        bstore(wp0[q] * inv[q], actp ? tbp + (unsigned)col0 * 4u : VOOB, rs);
        bstore(wp1[q] * inv[q], actp ? tbp + (unsigned)col1 * 4u : VOOB, rs);
        bstore(S[q], (actp && wv == 0 && li == 0) ? FBYTES + (unsigned)(tcur[q] - 1) * 4u : VOOB, rs);
      }
    }

    /* 7. w = p*g when live else init; truncation hi/lo split; publish X[n^1] */
    float w0[4], w1[4];
#pragma unroll
    for (int q = 0; q < 4; ++q) {
      const bool live = (tcur[q] >= ts[q]) & (tcur[q] < tend[q]);
      w0[q] = live ? p0[q] * gc0[q] : init0[q];
      w1[q] = live ? p1[q] * gc1[q] : init1[q];
      const int r = r0 + q;
      const unsigned sw = (unsigned)((r & 7) << 4);
      const unsigned off0 = wbase + (((unsigned)(r * 256 + col0 * 2)) ^ sw);
      const unsigned off1 = wbase + (((unsigned)(r * 256 + col1 * 2)) ^ sw);
      unsigned b0 = __builtin_bit_cast(unsigned, w0[q]);
      unsigned b1 = __builtin_bit_cast(unsigned, w1[q]);
      float hf0 = __builtin_bit_cast(float, b0 & 0xFFFF0000u);
      float hf1 = __builtin_bit_cast(float, b1 & 0xFFFF0000u);
      *(unsigned short*)(xh + off0) = (unsigned short)(b0 >> 16);
      *(unsigned short*)(xh + off1) = (unsigned short)(b1 >> 16);
      *(unsigned short*)(xl + off0) = (unsigned short)(__builtin_bit_cast(unsigned, w0[q] - hf0) >> 16);
      *(unsigned short*)(xl + off1) = (unsigned short)(__builtin_bit_cast(unsigned, w1[q] - hf1) >> 16);
    }

    /* 8. one LDS-only barrier per step */
    ldsbar();

    /* 9. rotate */
#pragma unroll
    for (int q = 0; q < 4; ++q) {
      wp0[q] = w0[q]; wp1[q] = w1[q];
      tcur[q] += 1;
      gc0[q] = gn0[q]; gc1[q] = gn1[q];
    }
  }
}

extern "C" void kernel_launch(void* const* d_in, const int* in_sizes, int n_in,
                              void* d_out, int out_size, void* d_ws, size_t ws_size,
                              hipStream_t stream) {
  const float* y  = (const float*)d_in[0];
  const float* tl = (const float*)d_in[1];
  const float* il = (const float*)d_in[2];
  const float* mu = (const float*)d_in[3];
  const float* ls = (const float*)d_in[4];

  float* wsf = (float*)d_ws;
  float* g   = wsf;                                 /* 67 MB */
  float* u0  = wsf + (size_t)TLEN * MST;
  unsigned short* GhiT = (unsigned short*)(u0 + MST);
  unsigned short* GloT = GhiT + MST * MST;
  float* isb  = (float*)(GloT + MST * MST);
  float* cstb = isb + MST * DOBS;

  build_params<<<MST + 1, MST, 0, stream>>>(tl, il, ls, GhiT, GloT, u0, isb, cstb);
  emis_kernel<<<TLEN / EROWS, MST, 0, stream>>>(y, mu, isb, cstb, g);
  hmm_scan<<<NBLK, 256, 0, stream>>>(g, GhiT, GloT, u0, (float*)d_out);
}

// Round 5
// 166.831 us; speedup vs baseline: 2.1748x; 1.6912x over previous
//
#include <hip/hip_runtime.h>
#include <math.h>

#define MST   128
#define DOBS  8
#define TLEN  131072
#define LOG2PI_F 1.8378770664093453f

#define CLEN   32
#define CHUNKS (TLEN / CLEN)          /* 4096 */
#define BCH    16                     /* chains (rows) per block */
#define NBLK   (CHUNKS / BCH)         /* 256 */
#define WARM   96
#define SSTAG  2
#define NSPAN  (SSTAG * (BCH - 1) + WARM + CLEN)   /* 158 */
#define EROWS  16

#define XBUF   (BCH * MST * 2)        /* 4096 bytes per X half-buffer */

#define FBYTES   ((unsigned)TLEN * MST * 4u)             /* f base   */
#define UTTBYTES (FBYTES + (unsigned)TLEN * 4u)          /* Utt base */
#define OUTBYTES (UTTBYTES + (unsigned)TLEN * MST * 4u)
#define VOOB 0xE0000000u

typedef __attribute__((ext_vector_type(8))) short v8s;
typedef __attribute__((ext_vector_type(4))) float v4f;
typedef __attribute__((ext_vector_type(4))) unsigned int v4u;

__device__ __forceinline__ unsigned short f2bf_rne(float x) {
  unsigned int b = __builtin_bit_cast(unsigned int, x);
  unsigned int r = b + 0x7FFFu + ((b >> 16) & 1u);
  return (unsigned short)(r >> 16);
}
__device__ __forceinline__ float bf2f(unsigned short h) {
  unsigned int b = ((unsigned int)h) << 16;
  return __builtin_bit_cast(float, b);
}
__device__ __forceinline__ v4u make_rsrc(const void* p, unsigned int bytes) {
  unsigned long long a = (unsigned long long)p;
  v4u r;
  r.x = (unsigned int)a;
  r.y = (unsigned int)(a >> 32) & 0xFFFFu;
  r.z = bytes;
  r.w = 0x00020000u;
  return r;
}
__device__ __forceinline__ void bstore(float v, unsigned int voff, v4u rs) {
  asm volatile("buffer_store_dword %0, %1, %2, 0 offen"
               :: "v"(v), "v"(voff), "s"(rs));
}
/* LDS-only barrier: order LDS, never drain vmcnt (stores stay in flight) */
__device__ __forceinline__ void ldsbar() {
  asm volatile("s_waitcnt lgkmcnt(0)" ::: "memory");
  __builtin_amdgcn_sched_barrier(0);
  __builtin_amdgcn_s_barrier();
  __builtin_amdgcn_sched_barrier(0);
}

/* ---------- kernel 1: Gamma (bf16 hi/lo, transposed) + u0 + emission consts ---------- */
__global__ void build_params(const float* __restrict__ tl,
                             const float* __restrict__ il,
                             const float* __restrict__ ls,
                             unsigned short* __restrict__ GhiT,
                             unsigned short* __restrict__ GloT,
                             float* __restrict__ u0,
                             float* __restrict__ isb,
                             float* __restrict__ cstb) {
  __shared__ float red[MST];
  const int j = threadIdx.x;
  const int b = blockIdx.x;
  float lg;
  if (b < MST) lg = (j == b) ? 0.0f : tl[b * (MST - 1) + (j > b ? j - 1 : j)];
  else         lg = il[j];
  float e = __expf(lg);
  red[j] = e;
  __syncthreads();
  for (int s = MST / 2; s > 0; s >>= 1) {
    if (j < s) red[j] += red[j + s];
    __syncthreads();
  }
  float val = e / red[0];
  if (b < MST) {
    unsigned short h = f2bf_rne(val);
    GhiT[j * MST + b] = h;                       /* Gamma^T: [dest][src] */
    GloT[j * MST + b] = f2bf_rne(val - bf2f(h));
  } else {
    u0[j] = val;
    float c = -((float)DOBS * 0.5f) * LOG2PI_F;
#pragma unroll
    for (int d = 0; d < DOBS; ++d) {
      float l = ls[j * DOBS + d];
      isb[j * DOBS + d] = __expf(-l);
      c -= l;
    }
    cstb[j] = c;
  }
}

/* ---------- kernel 2: emission densities, 16 rows per block ---------- */
__global__ void emis_kernel(const float* __restrict__ y,
                            const float* __restrict__ mu,
                            const float* __restrict__ isb,
                            const float* __restrict__ cstb,
                            float* __restrict__ g) {
  const int j  = threadIdx.x;
  const int tb = blockIdx.x * EROWS;
  __shared__ float ysh[EROWS * DOBS];
  ysh[j] = y[(unsigned)tb * DOBS + j];
  __syncthreads();
  float m[DOBS], is[DOBS];
  float cst = cstb[j];
#pragma unroll
  for (int d = 0; d < DOBS; ++d) { m[d] = mu[j * DOBS + d]; is[d] = isb[j * DOBS + d]; }
#pragma unroll
  for (int r = 0; r < EROWS; ++r) {
    float q = 0.0f;
#pragma unroll
    for (int d = 0; d < DOBS; ++d) {
      float z = (ysh[r * DOBS + d] - m[d]) * is[d];
      q = fmaf(z, z, q);
    }
    g[(unsigned)(tb + r) * MST + j] = __expf(fmaf(-0.5f, q, cst));
  }
}

/* ---------- kernel 3: 8-wave MFMA scan (16 cols/wave), 2 waves/SIMD ---------- */
__global__ __launch_bounds__(512, 2)
void hmm_scan(const float* __restrict__ g,
              const unsigned short* __restrict__ GhiT,
              const unsigned short* __restrict__ GloT,
              const float* __restrict__ u0,
              float* __restrict__ outbase) {
  __shared__ __align__(16) unsigned short Xh[2][BCH * MST];
  __shared__ __align__(16) unsigned short Xl[2][BCH * MST];
  char* xh = (char*)&Xh[0][0];
  char* xl = (char*)&Xl[0][0];

  const int tid = threadIdx.x;
  const int wv  = tid >> 6;          /* 0..7 */
  const int ln  = tid & 63;
  const int grp = ln >> 4;           /* 0..3: K-group for frags, row-group for C */
  const int li  = ln & 15;
  const int b   = blockIdx.x;
  const int col = wv * 16 + li;      /* ONE column per lane */

  const v4u rs = make_rsrc(outbase, OUTBYTES);

  /* B fragments: this wave's 16 columns of Gamma (hi+lo) */
  v8s Bh[4], Bl[4];
#pragma unroll
  for (int kt = 0; kt < 4; ++kt) {
    const int k = kt * 32 + grp * 8;
    Bh[kt] = *(const v8s*)(GhiT + col * MST + k);
    Bl[kt] = *(const v8s*)(GloT + col * MST + k);
  }
  const short bf1 = (short)0x3F80;
  const v8s ONE = {bf1, bf1, bf1, bf1, bf1, bf1, bf1, bf1};

  /* per-row (r = grp*4+q) bookkeeping */
  int t00[4], ts[4], tcur[4];
  float init[4];
  const float u0c = u0[col];
#pragma unroll
  for (int q = 0; q < 4; ++q) {
    const int r = grp * 4 + q;
    t00[q] = (b * BCH + r) * CLEN;
    int tsq = t00[q] - WARM; if (tsq < 0) tsq = 0;
    ts[q] = tsq;
    tcur[q] = t00[q] - WARM - SSTAG * r;
    init[q] = (tsq == 0) ? u0c : (1.0f / MST);
  }

  /* prologue: publish X[0] = init, prefetch g */
  float wp[4], gc[4];
#pragma unroll
  for (int q = 0; q < 4; ++q) {
    wp[q] = init[q];
    const int r = grp * 4 + q;
    const unsigned off = ((unsigned)(r * 256 + col * 2)) ^ (unsigned)((r & 7) << 4);
    unsigned short h = f2bf_rne(wp[q]);
    *(unsigned short*)(xh + off) = h;
    *(unsigned short*)(xl + off) = (unsigned short)(__builtin_bit_cast(unsigned, wp[q] - bf2f(h)) >> 16);
    int tm = tcur[q]; tm = tm < 0 ? 0 : (tm > TLEN - 1 ? TLEN - 1 : tm);
    gc[q] = g[(unsigned)tm * MST + col];
  }
  ldsbar();

  for (int n = 0; n <= NSPAN; ++n) {
    const unsigned rbase = (unsigned)(n & 1) * XBUF;
    const unsigned wbase = rbase ^ XBUF;

    /* 1. A-fragments of W̃_{n-1} (shared across all 8 waves) */
    v8s Ah[4], Al[4];
#pragma unroll
    for (int kt = 0; kt < 4; ++kt) {
      const unsigned off = rbase + (((unsigned)(li * 256 + kt * 64 + grp * 16)) ^ ((unsigned)((li & 7) << 4)));
      Ah[kt] = *(const v8s*)(xh + off);
      Al[kt] = *(const v8s*)(xl + off);
    }

    /* 2. row sums via hi-part MFMA vs ones (RNE hi → signed error ~3e-5) */
    v4f Cs = {0.f, 0.f, 0.f, 0.f};
#pragma unroll
    for (int kt = 0; kt < 4; ++kt)
      Cs = __builtin_amdgcn_mfma_f32_16x16x32_bf16(Ah[kt], ONE, Cs, 0, 0, 0);

    /* 3. P̃ = W̃ @ Γ, 3-term compensated */
    v4f Ca = {0.f,0.f,0.f,0.f}, Cb = {0.f,0.f,0.f,0.f}, Cc = {0.f,0.f,0.f,0.f};
#pragma unroll
    for (int kt = 0; kt < 4; ++kt) {
      Ca = __builtin_amdgcn_mfma_f32_16x16x32_bf16(Ah[kt], Bh[kt], Ca, 0, 0, 0);
      Cb = __builtin_amdgcn_mfma_f32_16x16x32_bf16(Al[kt], Bh[kt], Cb, 0, 0, 0);
      Cc = __builtin_amdgcn_mfma_f32_16x16x32_bf16(Ah[kt], Bl[kt], Cc, 0, 0, 0);
    }

    /* 4. prefetch next g (one-step slack; counted vmcnt at use) */
    float gn[4];
#pragma unroll
    for (int q = 0; q < 4; ++q) {
      int tm = tcur[q] + 1; tm = tm < 0 ? 0 : (tm > TLEN - 1 ? TLEN - 1 : tm);
      gn[q] = g[(unsigned)tm * MST + col];
    }

    /* 5. normalize; stores (fire-and-forget, OOB-gated) */
    float S[4], inv[4], p[4];
#pragma unroll
    for (int q = 0; q < 4; ++q) {
      S[q] = Cs[q];
      inv[q] = __builtin_amdgcn_rcpf(S[q]);
      p[q] = ((Ca[q] + Cb[q]) + Cc[q]) * inv[q];
    }
    if (n >= WARM) {
#pragma unroll
      for (int q = 0; q < 4; ++q) {
        const bool act  = (unsigned)(tcur[q] - t00[q]) < (unsigned)CLEN;
        const bool actp = (unsigned)(tcur[q] - 1 - t00[q]) < (unsigned)CLEN;
        const unsigned tb = (unsigned)tcur[q] * 512u;
        bstore(p[q], act ? UTTBYTES + tb + (unsigned)col * 4u : VOOB, rs);
        bstore(wp[q] * inv[q], actp ? tb - 512u + (unsigned)col * 4u : VOOB, rs);
        bstore(S[q], (actp && wv == 0 && li == 0) ? FBYTES + (unsigned)(tcur[q] - 1) * 4u : VOOB, rs);
      }
    }

    /* 6. w update (hold init outside live window), RNE split, publish */
    float w[4];
#pragma unroll
    for (int q = 0; q < 4; ++q) {
      const bool live = (tcur[q] >= ts[q]) & (tcur[q] < t00[q] + CLEN);
      w[q] = live ? p[q] * gc[q] : init[q];
      const int r = grp * 4 + q;
      const unsigned off = wbase + (((unsigned)(r * 256 + col * 2)) ^ ((unsigned)((r & 7) << 4)));
      unsigned bb = __builtin_bit_cast(unsigned, w[q]);
      unsigned ru = bb + 0x7FFFu + ((bb >> 16) & 1u);
      float hf = __builtin_bit_cast(float, ru & 0xFFFF0000u);
      *(unsigned short*)(xh + off) = (unsigned short)(ru >> 16);
      *(unsigned short*)(xl + off) = (unsigned short)(__builtin_bit_cast(unsigned, w[q] - hf) >> 16);
    }

    /* 7. single LDS-only barrier per step */
    ldsbar();

    /* 8. rotate */
#pragma unroll
    for (int q = 0; q < 4; ++q) {
      wp[q] = w[q];
      tcur[q] += 1;
      gc[q] = gn[q];
    }
  }
}

extern "C" void kernel_launch(void* const* d_in, const int* in_sizes, int n_in,
                              void* d_out, int out_size, void* d_ws, size_t ws_size,
                              hipStream_t stream) {
  const float* y  = (const float*)d_in[0];
  const float* tl = (const float*)d_in[1];
  const float* il = (const float*)d_in[2];
  const float* mu = (const float*)d_in[3];
  const float* ls = (const float*)d_in[4];

  float* wsf = (float*)d_ws;
  float* g   = wsf;                                 /* 67 MB */
  float* u0  = wsf + (size_t)TLEN * MST;
  unsigned short* GhiT = (unsigned short*)(u0 + MST);
  unsigned short* GloT = GhiT + MST * MST;
  float* isb  = (float*)(GloT + MST * MST);
  float* cstb = isb + MST * DOBS;

  build_params<<<MST + 1, MST, 0, stream>>>(tl, il, ls, GhiT, GloT, u0, isb, cstb);
  emis_kernel<<<TLEN / EROWS, MST, 0, stream>>>(y, mu, isb, cstb, g);
  hmm_scan<<<NBLK, 512, 0, stream>>>(g, GhiT, GloT, u0, (float*)d_out);
}

// Round 6
// 154.242 us; speedup vs baseline: 2.3523x; 1.0816x over previous
//
#include <hip/hip_runtime.h>
#include <math.h>

#define MST   128
#define DOBS  8
#define TLEN  131072
#define LOG2PI_F 1.8378770664093453f

#define CLEN   32
#define CHUNKS (TLEN / CLEN)          /* 4096 */
#define BCH    16                     /* chains (rows) per block */
#define NBLK   (CHUNKS / BCH)         /* 256 */
#define WARM   96
#define SSTAG  2
#define NITER  160                    /* >= WARM + SSTAG*15 + CLEN = 158, even */
#define EROWS  16
#define GPAD   128                    /* padding rows before/after g */

#define XELEMS (BCH * MST)            /* 2048 halfwords per plane */

typedef __attribute__((ext_vector_type(8))) short v8s;
typedef __attribute__((ext_vector_type(4))) float v4f;

__device__ __forceinline__ unsigned short f2bf_rne(float x) {
  unsigned int b = __builtin_bit_cast(unsigned int, x);
  unsigned int r = b + 0x7FFFu + ((b >> 16) & 1u);
  return (unsigned short)(r >> 16);
}
__device__ __forceinline__ float bf2f(unsigned short h) {
  unsigned int b = ((unsigned int)h) << 16;
  return __builtin_bit_cast(float, b);
}
/* LDS-only barrier: order LDS, never drain vmcnt (stores stay in flight) */
__device__ __forceinline__ void ldsbar() {
  asm volatile("s_waitcnt lgkmcnt(0)" ::: "memory");
  __builtin_amdgcn_sched_barrier(0);
  __builtin_amdgcn_s_barrier();
  __builtin_amdgcn_sched_barrier(0);
}

/* ---------- kernel 1: Gamma (bf16 hi/lo, transposed) + u0 + emission consts ---------- */
__global__ void build_params(const float* __restrict__ tl,
                             const float* __restrict__ il,
                             const float* __restrict__ ls,
                             unsigned short* __restrict__ GhiT,
                             unsigned short* __restrict__ GloT,
                             float* __restrict__ u0,
                             float* __restrict__ isb,
                             float* __restrict__ cstb) {
  __shared__ float red[MST];
  const int j = threadIdx.x;
  const int b = blockIdx.x;
  float lg;
  if (b < MST) lg = (j == b) ? 0.0f : tl[b * (MST - 1) + (j > b ? j - 1 : j)];
  else         lg = il[j];
  float e = __expf(lg);
  red[j] = e;
  __syncthreads();
  for (int s = MST / 2; s > 0; s >>= 1) {
    if (j < s) red[j] += red[j + s];
    __syncthreads();
  }
  float val = e / red[0];
  if (b < MST) {
    unsigned short h = f2bf_rne(val);
    GhiT[j * MST + b] = h;                       /* Gamma^T: [dest][src] */
    GloT[j * MST + b] = f2bf_rne(val - bf2f(h));
  } else {
    u0[j] = val;
    float c = -((float)DOBS * 0.5f) * LOG2PI_F;
#pragma unroll
    for (int d = 0; d < DOBS; ++d) {
      float l = ls[j * DOBS + d];
      isb[j * DOBS + d] = __expf(-l);
      c -= l;
    }
    cstb[j] = c;
  }
}

/* ---------- kernel 2: emission densities, 16 rows per block ---------- */
__global__ void emis_kernel(const float* __restrict__ y,
                            const float* __restrict__ mu,
                            const float* __restrict__ isb,
                            const float* __restrict__ cstb,
                            float* __restrict__ g0) {
  const int j  = threadIdx.x;
  const int tb = blockIdx.x * EROWS;
  __shared__ float ysh[EROWS * DOBS];
  ysh[j] = y[(unsigned)tb * DOBS + j];
  __syncthreads();
  float m[DOBS], is[DOBS];
  float cst = cstb[j];
#pragma unroll
  for (int d = 0; d < DOBS; ++d) { m[d] = mu[j * DOBS + d]; is[d] = isb[j * DOBS + d]; }
#pragma unroll
  for (int r = 0; r < EROWS; ++r) {
    float q = 0.0f;
#pragma unroll
    for (int d = 0; d < DOBS; ++d) {
      float z = (ysh[r * DOBS + d] - m[d]) * is[d];
      q = fmaf(z, z, q);
    }
    g0[(unsigned)(tb + r) * MST + j] = __expf(fmaf(-0.5f, q, cst));
  }
}

/* ---------- kernel 3: 8-wave MFMA scan; all VMEM compiler-visible ---------- */
__global__ __launch_bounds__(512, 2)
void hmm_scan(const float* __restrict__ gfull,   /* padded base: g[t] at (t+GPAD)*MST */
              const unsigned short* __restrict__ GhiT,
              const unsigned short* __restrict__ GloT,
              const float* __restrict__ u0,
              float* __restrict__ outUt,
              float* __restrict__ outF,
              float* __restrict__ outUtt) {
  __shared__ __align__(16) unsigned short Xh[2][XELEMS];
  __shared__ __align__(16) unsigned short Xl[2][XELEMS];

  const int tid = threadIdx.x;
  const int wv  = tid >> 6;          /* 0..7 */
  const int ln  = tid & 63;
  const int grp = ln >> 4;           /* 0..3 */
  const int li  = ln & 15;
  const int b   = blockIdx.x;
  const int col = wv * 16 + li;      /* one state column per lane */
  const unsigned col4 = (unsigned)col * 4u;
  const bool fstorer = (wv == 0) && (li == 0);

  /* B fragments: this wave's 16 columns of Gamma (hi+lo) */
  v8s Bh[4], Bl[4];
#pragma unroll
  for (int kt = 0; kt < 4; ++kt) {
    const int k = kt * 32 + grp * 8;
    Bh[kt] = *(const v8s*)(GhiT + col * MST + k);
    Bl[kt] = *(const v8s*)(GloT + col * MST + k);
  }
  const short bf1 = (short)0x3F80;
  const v8s ONE = {bf1, bf1, bf1, bf1, bf1, bf1, bf1, bf1};

  /* precomputed swizzled LDS offsets */
  unsigned offA[4], offW[4];
#pragma unroll
  for (int kt = 0; kt < 4; ++kt)
    offA[kt] = ((unsigned)(li * 256 + kt * 64 + grp * 16)) ^ ((unsigned)((li & 7) << 4));
#pragma unroll
  for (int q = 0; q < 4; ++q) {
    const int r = grp * 4 + q;
    offW[q] = ((unsigned)(r * 256 + col * 2)) ^ ((unsigned)((r & 7) << 4));
  }

  /* per-row bookkeeping (all in d = tcur - t00 coordinates) */
  int dlo[4], dcur[4];
  unsigned toff[4], goff[4];
  float init[4];
  const float u0c = u0[col];
#pragma unroll
  for (int q = 0; q < 4; ++q) {
    const int r = grp * 4 + q;
    const int t00 = (b * BCH + r) * CLEN;
    int ts = t00 - WARM; if (ts < 0) ts = 0;
    const int tcur0 = t00 - WARM - SSTAG * r;
    dlo[q]  = ts - t00;                       /* live when dcur >= dlo */
    dcur[q] = tcur0 - t00;                    /* = -(WARM + SSTAG*r) */
    toff[q] = (unsigned)tcur0 * 512u;         /* wraps while negative; unused then */
    goff[q] = (unsigned)((tcur0 + 2 + GPAD) * (MST * 4)) + col4;
    init[q] = (ts == 0) ? u0c : (1.0f / MST);
  }

  /* prologue: publish X[0] = init, prefetch g depth-2 */
  float wp[4], gc[4], g1[4];
#pragma unroll
  for (int q = 0; q < 4; ++q) {
    wp[q] = init[q];
    unsigned bw = __builtin_bit_cast(unsigned, wp[q]);
    float hf = __builtin_bit_cast(float, bw & 0xFFFF0000u);
    *(unsigned short*)((char*)&Xh[0][0] + offW[q]) = (unsigned short)(bw >> 16);
    *(unsigned short*)((char*)&Xl[0][0] + offW[q]) =
        (unsigned short)(__builtin_bit_cast(unsigned, wp[q] - hf) >> 16);
    gc[q] = *(const float*)((const char*)gfull + (goff[q] - 1024u));
    g1[q] = *(const float*)((const char*)gfull + (goff[q] - 512u));
  }
  ldsbar();

#pragma unroll 2
  for (int n = 0; n < NITER; ++n) {
    const unsigned short* xhp = &Xh[n & 1][0];
    const unsigned short* xlp = &Xl[n & 1][0];
    unsigned short* xhw = &Xh[(n & 1) ^ 1][0];
    unsigned short* xlw = &Xl[(n & 1) ^ 1][0];

    /* 1. A-fragments of W̃ (hi+lo) */
    v8s Ah[4], Al[4];
#pragma unroll
    for (int kt = 0; kt < 4; ++kt) {
      Ah[kt] = *(const v8s*)((const char*)xhp + offA[kt]);
      Al[kt] = *(const v8s*)((const char*)xlp + offA[kt]);
    }

    /* 2. g prefetch (depth 2, padded buffer, compiler-tracked) */
    float g2[4];
#pragma unroll
    for (int q = 0; q < 4; ++q) {
      g2[q] = *(const float*)((const char*)gfull + goff[q]);
      goff[q] += 512u;
    }

    /* 3. rowsum (2-deep chains) + matvec (3-term compensated, 2-deep chains) */
    v4f Cs1 = {0,0,0,0}, Cs2 = {0,0,0,0};
    v4f Ca = {0,0,0,0}, Cb = {0,0,0,0};
    v4f Cc1 = {0,0,0,0}, Cc2 = {0,0,0,0};
    v4f Cd1 = {0,0,0,0}, Cd2 = {0,0,0,0};
    Cs1 = __builtin_amdgcn_mfma_f32_16x16x32_bf16(Ah[0], ONE, Cs1, 0, 0, 0);
    Cs1 = __builtin_amdgcn_mfma_f32_16x16x32_bf16(Ah[1], ONE, Cs1, 0, 0, 0);
    Cs2 = __builtin_amdgcn_mfma_f32_16x16x32_bf16(Ah[2], ONE, Cs2, 0, 0, 0);
    Cs2 = __builtin_amdgcn_mfma_f32_16x16x32_bf16(Ah[3], ONE, Cs2, 0, 0, 0);
    Ca  = __builtin_amdgcn_mfma_f32_16x16x32_bf16(Ah[0], Bh[0], Ca, 0, 0, 0);
    Ca  = __builtin_amdgcn_mfma_f32_16x16x32_bf16(Ah[1], Bh[1], Ca, 0, 0, 0);
    Cb  = __builtin_amdgcn_mfma_f32_16x16x32_bf16(Ah[2], Bh[2], Cb, 0, 0, 0);
    Cb  = __builtin_amdgcn_mfma_f32_16x16x32_bf16(Ah[3], Bh[3], Cb, 0, 0, 0);
    Cc1 = __builtin_amdgcn_mfma_f32_16x16x32_bf16(Al[0], Bh[0], Cc1, 0, 0, 0);
    Cc1 = __builtin_amdgcn_mfma_f32_16x16x32_bf16(Al[1], Bh[1], Cc1, 0, 0, 0);
    Cc2 = __builtin_amdgcn_mfma_f32_16x16x32_bf16(Al[2], Bh[2], Cc2, 0, 0, 0);
    Cc2 = __builtin_amdgcn_mfma_f32_16x16x32_bf16(Al[3], Bh[3], Cc2, 0, 0, 0);
    Cd1 = __builtin_amdgcn_mfma_f32_16x16x32_bf16(Ah[0], Bl[0], Cd1, 0, 0, 0);
    Cd1 = __builtin_amdgcn_mfma_f32_16x16x32_bf16(Ah[1], Bl[1], Cd1, 0, 0, 0);
    Cd2 = __builtin_amdgcn_mfma_f32_16x16x32_bf16(Ah[2], Bl[2], Cd2, 0, 0, 0);
    Cd2 = __builtin_amdgcn_mfma_f32_16x16x32_bf16(Ah[3], Bl[3], Cd2, 0, 0, 0);

    /* 4. normalize, update, publish */
    float S[4], inv[4], p[4], w[4];
#pragma unroll
    for (int q = 0; q < 4; ++q) {
      S[q] = Cs1[q] + Cs2[q];
      inv[q] = __builtin_amdgcn_rcpf(S[q]);
      p[q] = (((Ca[q] + Cb[q]) + (Cc1[q] + Cc2[q])) + (Cd1[q] + Cd2[q])) * inv[q];
      const bool live = (dcur[q] >= dlo[q]) & (dcur[q] < CLEN);
      w[q] = live ? p[q] * gc[q] : init[q];
      unsigned bw = __builtin_bit_cast(unsigned, w[q]);
      float hf = __builtin_bit_cast(float, bw & 0xFFFF0000u);
      *(unsigned short*)((char*)xhw + offW[q]) = (unsigned short)(bw >> 16);
      *(unsigned short*)((char*)xlw + offW[q]) =
          (unsigned short)(__builtin_bit_cast(unsigned, w[q] - hf) >> 16);
    }

    /* 5. output stores: compiler-visible, branch-gated (skip-on-execz) */
    if (n >= WARM) {
#pragma unroll
      for (int q = 0; q < 4; ++q) {
        if ((unsigned)dcur[q] < (unsigned)CLEN)
          *(float*)((char*)outUtt + (toff[q] + col4)) = p[q];
        if ((unsigned)(dcur[q] - 1) < (unsigned)CLEN) {
          *(float*)((char*)outUt + (toff[q] - 512u + col4)) = wp[q] * inv[q];
          if (fstorer)
            *(float*)((char*)outF + ((toff[q] >> 7) - 4u)) = S[q];
        }
      }
    }

    /* 6. single LDS-only barrier per step */
    ldsbar();

    /* 7. rotate */
#pragma unroll
    for (int q = 0; q < 4; ++q) {
      wp[q] = w[q];
      gc[q] = g1[q]; g1[q] = g2[q];
      dcur[q] += 1;
      toff[q] += 512u;
    }
  }
}

extern "C" void kernel_launch(void* const* d_in, const int* in_sizes, int n_in,
                              void* d_out, int out_size, void* d_ws, size_t ws_size,
                              hipStream_t stream) {
  const float* y  = (const float*)d_in[0];
  const float* tl = (const float*)d_in[1];
  const float* il = (const float*)d_in[2];
  const float* mu = (const float*)d_in[3];
  const float* ls = (const float*)d_in[4];

  /* ws layout: padded g | u0 | GhiT | GloT | isb | cstb  (~67.4 MB) */
  float* wsf   = (float*)d_ws;
  float* gfull = wsf;                                   /* (GPAD+TLEN+GPAD) x MST */
  float* g0    = gfull + (size_t)GPAD * MST;
  float* u0    = gfull + (size_t)(TLEN + 2 * GPAD) * MST;
  unsigned short* GhiT = (unsigned short*)(u0 + MST);
  unsigned short* GloT = GhiT + MST * MST;
  float* isb  = (float*)(GloT + MST * MST);
  float* cstb = isb + MST * DOBS;

  float* outUt  = (float*)d_out;
  float* outF   = outUt + (size_t)TLEN * MST;
  float* outUtt = outF + TLEN;

  build_params<<<MST + 1, MST, 0, stream>>>(tl, il, ls, GhiT, GloT, u0, isb, cstb);
  emis_kernel<<<TLEN / EROWS, MST, 0, stream>>>(y, mu, isb, cstb, g0);
  hmm_scan<<<NBLK, 512, 0, stream>>>(gfull, GhiT, GloT, u0, outUt, outF, outUtt);
}

// Round 7
// 146.389 us; speedup vs baseline: 2.4785x; 1.0536x over previous
//
#include <hip/hip_runtime.h>
#include <math.h>

#define MST   128
#define DOBS  8
#define TLEN  131072
#define LOG2PI_F 1.8378770664093453f

#define CLEN  16
#define NW    (TLEN / CLEN / 16)   /* 512 independent waves */
#define WARM  96
#define LEAN  72                   /* hi-only state packing before this step */
#define NSTEP (WARM + CLEN)        /* 112 */
#define GPAD  128
#define EROWS 16

typedef __attribute__((ext_vector_type(8))) short v8s;
typedef __attribute__((ext_vector_type(4))) float v4f;
typedef __attribute__((ext_vector_type(4))) unsigned int v4u;

__device__ __forceinline__ unsigned short f2bf_rne(float x) {
  unsigned int b = __builtin_bit_cast(unsigned int, x);
  unsigned int r = b + 0x7FFFu + ((b >> 16) & 1u);
  return (unsigned short)(r >> 16);
}
__device__ __forceinline__ unsigned cvtpk(float a, float b) {
  unsigned r;
  asm("v_cvt_pk_bf16_f32 %0, %1, %2" : "=v"(r) : "v"(a), "v"(b));
  return r;
}

/* ---------- kernel 1: plain Gamma (f32, [src][dst]) + u0 + emission consts ---------- */
__global__ void build_params(const float* __restrict__ tl,
                             const float* __restrict__ il,
                             const float* __restrict__ ls,
                             float* __restrict__ Gf,
                             float* __restrict__ u0,
                             float* __restrict__ isb,
                             float* __restrict__ cstb) {
  __shared__ float red[MST];
  const int j = threadIdx.x;
  const int b = blockIdx.x;
  float lg;
  if (b < MST) lg = (j == b) ? 0.0f : tl[b * (MST - 1) + (j > b ? j - 1 : j)];
  else         lg = il[j];
  float e = __expf(lg);
  red[j] = e;
  __syncthreads();
  for (int s = MST / 2; s > 0; s >>= 1) {
    if (j < s) red[j] += red[j + s];
    __syncthreads();
  }
  float val = e / red[0];
  if (b < MST) {
    Gf[b * MST + j] = val;                      /* Gamma[src=b][dst=j] */
  } else {
    u0[j] = val;
    float c = -((float)DOBS * 0.5f) * LOG2PI_F;
#pragma unroll
    for (int d = 0; d < DOBS; ++d) {
      float l = ls[j * DOBS + d];
      isb[j * DOBS + d] = __expf(-l);
      c -= l;
    }
    cstb[j] = c;
  }
}

/* ---------- kernel 1b: permuted Gamma^T A-fragments (bf16 RNE) ----------
   A-frag element (tile m, ktile kt, lane l, j):
     row i = l&15  -> global hw row 16m+i -> logical dst = lam(16m+i)
     k = (l>>4)*8 + j + 32kt = logical src (identity labeling)            */
__global__ void build_afrag(const float* __restrict__ Gf,
                            unsigned short* __restrict__ GA) {
  const int idx = blockIdx.x * 64 + threadIdx.x;  /* (m*4+kt)*64 + l */
  const int l  = idx & 63;
  const int mk = idx >> 6;
  const int kt = mk & 3, m = mk >> 2;
  const int i  = l & 15, hh = l >> 4;
  const int rg = 16 * m + i;
  const int lam = ((rg >> 5) << 5) | (((rg >> 2) & 3) << 3) | (((rg >> 4) & 1) << 2) | (rg & 3);
  unsigned short o[8];
#pragma unroll
  for (int j = 0; j < 8; ++j) {
    const int src = 32 * kt + 8 * hh + j;
    o[j] = f2bf_rne(Gf[src * MST + lam]);
  }
  v4u* dst = (v4u*)(GA + (size_t)idx * 8);
  *dst = *(const v4u*)o;
}

/* ---------- kernel 2: emission densities (natural state order) ---------- */
__global__ void emis_kernel(const float* __restrict__ y,
                            const float* __restrict__ mu,
                            const float* __restrict__ isb,
                            const float* __restrict__ cstb,
                            float* __restrict__ g0) {
  const int j  = threadIdx.x;
  const int tb = blockIdx.x * EROWS;
  __shared__ float ysh[EROWS * DOBS];
  ysh[j] = y[(unsigned)tb * DOBS + j];
  __syncthreads();
  float m[DOBS], is[DOBS];
  float cst = cstb[j];
#pragma unroll
  for (int d = 0; d < DOBS; ++d) { m[d] = mu[j * DOBS + d]; is[d] = isb[j * DOBS + d]; }
#pragma unroll
  for (int r = 0; r < EROWS; ++r) {
    float q = 0.0f;
#pragma unroll
    for (int d = 0; d < DOBS; ++d) {
      float z = (ysh[r * DOBS + d] - m[d]) * is[d];
      q = fmaf(z, z, q);
    }
    g0[(unsigned)(tb + r) * MST + j] = __expf(fmaf(-0.5f, q, cst));
  }
}

/* ---------- scan helpers ---------- */
__device__ __forceinline__ void loadg(v4f* gc, const float* gfull, unsigned gvo) {
#pragma unroll
  for (int m = 0; m < 8; ++m)
    gc[m] = *(const v4f*)((const char*)gfull + (gvo + (m >> 1) * 128 + (m & 1) * 16));
}

__device__ __forceinline__ void packB(const v4f* w, v8s* Bh, v8s* Bl, bool full) {
#pragma unroll
  for (int kt = 0; kt < 4; ++kt) {
    const v4f wa = w[2 * kt], wb = w[2 * kt + 1];
    const unsigned r0 = cvtpk(wa[0], wa[1]), r1 = cvtpk(wa[2], wa[3]);
    const unsigned r2 = cvtpk(wb[0], wb[1]), r3 = cvtpk(wb[2], wb[3]);
    Bh[kt] = __builtin_bit_cast(v8s, (v4u){r0, r1, r2, r3});
    if (full) {
      const float l0 = wa[0] - __builtin_bit_cast(float, r0 << 16);
      const float l1 = wa[1] - __builtin_bit_cast(float, r0 & 0xFFFF0000u);
      const float l2 = wa[2] - __builtin_bit_cast(float, r1 << 16);
      const float l3 = wa[3] - __builtin_bit_cast(float, r1 & 0xFFFF0000u);
      const float l4 = wb[0] - __builtin_bit_cast(float, r2 << 16);
      const float l5 = wb[1] - __builtin_bit_cast(float, r2 & 0xFFFF0000u);
      const float l6 = wb[2] - __builtin_bit_cast(float, r3 << 16);
      const float l7 = wb[3] - __builtin_bit_cast(float, r3 & 0xFFFF0000u);
      const unsigned s0 = cvtpk(l0, l1), s1 = cvtpk(l2, l3);
      const unsigned s2 = cvtpk(l4, l5), s3 = cvtpk(l6, l7);
      Bl[kt] = __builtin_bit_cast(v8s, (v4u){s0, s1, s2, s3});
    }
  }
}

template<bool FULL, bool LIVE, bool REIN>
__device__ __forceinline__ void scan_step(
    int n, int wid, int c, int h,
    const v8s* A, v8s* Bh, v8s* Bl, v4f* w, v4f* gc,
    float& inv, unsigned& gvo, unsigned& uvo,
    const float* gfull, const float* u0,
    float* outUt, float* outF, float* outUtt) {
  /* 1. D = W~ @ Gamma (2-term exact-state split, Gamma hi) */
  v4f D[8] = {};
#pragma unroll
  for (int kt = 0; kt < 4; ++kt)
#pragma unroll
    for (int m = 0; m < 8; ++m)
      D[m] = __builtin_amdgcn_mfma_f32_16x16x32_bf16(A[m * 4 + kt], Bh[kt], D[m], 0, 0, 0);
  if (FULL) {
#pragma unroll
    for (int kt = 0; kt < 4; ++kt)
#pragma unroll
      for (int m = 0; m < 8; ++m)
        D[m] = __builtin_amdgcn_mfma_f32_16x16x32_bf16(A[m * 4 + kt], Bl[kt], D[m], 0, 0, 0);
  }
  /* 2. fold inv_{n-1} into g */
#pragma unroll
  for (int m = 0; m < 8; ++m) gc[m] *= inv;
  /* 3. predicted dist -> Utt */
  if (LIVE) {
#pragma unroll
    for (int m = 0; m < 8; ++m) {
      v4f p = D[m] * inv;
      *(v4f*)((char*)outUtt + (uvo + (m >> 1) * 128 + (m & 1) * 16)) = p;
    }
  }
  /* 4. w~ = p~ * g */
#pragma unroll
  for (int m = 0; m < 8; ++m) w[m] = D[m] * gc[m];
  /* 5. exact u0 (re)injection for early chains (wave 0 only) */
  if (REIN) {
    if (wid == 0 && ((n & 15) == 15)) {
      const int ctar = (95 - n) >> 4;
#pragma unroll
      for (int m = 0; m < 8; ++m) {
        v4f uv = *(const v4f*)(u0 + (m >> 1) * 32 + h * 8 + (m & 1) * 4);
        if (c == ctar) w[m] = uv;
      }
    }
  }
  /* 6. prefetch next g (gc dead; ~full step of latency slack) */
  loadg(gc, gfull, gvo);
  gvo += 512u;
  /* 7. rowsum S = f_t (f32 exact) + cross-h reduce */
  v4f a0 = w[0] + w[1], a1 = w[2] + w[3], a2 = w[4] + w[5], a3 = w[6] + w[7];
  v4f a4 = a0 + a1, a5 = a2 + a3, a6 = a4 + a5;
  float s = (a6[0] + a6[1]) + (a6[2] + a6[3]);
  s += __shfl_xor(s, 16);
  s += __shfl_xor(s, 32);
  const float invn = __builtin_amdgcn_rcpf(s);
  /* 8. repack state for next step (layout-closed: no cross-lane moves) */
  packB(w, Bh, Bl, FULL);
  /* 9. filtered dist + f */
  if (LIVE) {
#pragma unroll
    for (int m = 0; m < 8; ++m) {
      v4f ut = w[m] * invn;
      *(v4f*)((char*)outUt + (uvo + (m >> 1) * 128 + (m & 1) * 16)) = ut;
    }
    if (h == 0) *(float*)((char*)outF + (uvo >> 7)) = s;
  }
  uvo += 512u;
  inv = invn;
}

/* ---------- kernel 3: barrier-free in-register MFMA scan, 1 wave = 16 chains ---------- */
__global__ __launch_bounds__(64, 1)
void hmm_scan(const float* __restrict__ gfull,
              const unsigned short* __restrict__ GA,
              const float* __restrict__ u0,
              float* __restrict__ outUt,
              float* __restrict__ outF,
              float* __restrict__ outUtt) {
  const int l = threadIdx.x;
  const int h = l >> 4, c = l & 15;
  const int wid = blockIdx.x;
  const int t00 = (wid * 16 + c) * CLEN;

  /* Gamma^T A-fragments: 32 x v8s = 128 VGPR, loop-invariant */
  v8s A[32];
#pragma unroll
  for (int f = 0; f < 32; ++f)
    A[f] = *(const v8s*)(GA + (size_t)(f * 64 + l) * 8);

  /* initial state: uniform; chain 6 of wave 0 starts exactly at u0 */
  v4f w[8];
#pragma unroll
  for (int m = 0; m < 8; ++m)
    w[m] = (v4f){1.0f / MST, 1.0f / MST, 1.0f / MST, 1.0f / MST};
  if (wid == 0) {
#pragma unroll
    for (int m = 0; m < 8; ++m) {
      v4f uv = *(const v4f*)(u0 + (m >> 1) * 32 + h * 8 + (m & 1) * 4);
      if (c == 6) w[m] = uv;
    }
  }
  float inv = 1.0f;  /* both inits sum to exactly 1 */

  v8s Bh[4], Bl[4];
  packB(w, Bh, Bl, true);

  unsigned gvo = (unsigned)((t00 - WARM + GPAD) * 512 + h * 32);
  v4f gc[8];
  loadg(gc, gfull, gvo);
  gvo += 512u;
  unsigned uvo = (unsigned)((t00 - WARM) * 512 + h * 32);

  for (int n = 0; n < LEAN; ++n)
    scan_step<false, false, true>(n, wid, c, h, A, Bh, Bl, w, gc, inv, gvo, uvo,
                                  gfull, u0, outUt, outF, outUtt);
  for (int n = LEAN; n < WARM; ++n)
    scan_step<true, false, true>(n, wid, c, h, A, Bh, Bl, w, gc, inv, gvo, uvo,
                                 gfull, u0, outUt, outF, outUtt);
  for (int n = WARM; n < NSTEP; ++n)
    scan_step<true, true, false>(n, wid, c, h, A, Bh, Bl, w, gc, inv, gvo, uvo,
                                 gfull, u0, outUt, outF, outUtt);
}

extern "C" void kernel_launch(void* const* d_in, const int* in_sizes, int n_in,
                              void* d_out, int out_size, void* d_ws, size_t ws_size,
                              hipStream_t stream) {
  const float* y  = (const float*)d_in[0];
  const float* tl = (const float*)d_in[1];
  const float* il = (const float*)d_in[2];
  const float* mu = (const float*)d_in[3];
  const float* ls = (const float*)d_in[4];

  /* ws: padded g | u0 | Gf | GA | isb | cstb (~67.35 MB) */
  float* wsf   = (float*)d_ws;
  float* gfull = wsf;                                    /* (GPAD+TLEN+GPAD) x MST */
  float* g0    = gfull + (size_t)GPAD * MST;
  float* u0    = gfull + (size_t)(TLEN + 2 * GPAD) * MST;
  float* Gf    = u0 + MST;
  unsigned short* GA = (unsigned short*)(Gf + MST * MST);
  float* isb  = (float*)(GA + 8 * 4 * 64 * 8);
  float* cstb = isb + MST * DOBS;

  float* outUt  = (float*)d_out;
  float* outF   = outUt + (size_t)TLEN * MST;
  float* outUtt = outF + TLEN;

  build_params<<<MST + 1, MST, 0, stream>>>(tl, il, ls, Gf, u0, isb, cstb);
  build_afrag<<<32, 64, 0, stream>>>(Gf, GA);
  emis_kernel<<<TLEN / EROWS, MST, 0, stream>>>(y, mu, isb, cstb, g0);
  hmm_scan<<<NW, 64, 0, stream>>>(gfull, GA, u0, outUt, outF, outUtt);
}

// Round 8
// 91.948 us; speedup vs baseline: 3.9459x; 1.5921x over previous
//
#include <hip/hip_runtime.h>
#include <math.h>

#define MST   128
#define DOBS  8
#define TLEN  131072
#define LOG2PI_F 1.8378770664093453f

#define CLEN  8
#define NW    (TLEN / CLEN / 16)   /* 1024 waves: one per SIMD */
#define WARM  48
#define NSTEP (WARM + CLEN)        /* 56 */
#define GPAD  128
#define EROWS 16

typedef __attribute__((ext_vector_type(8))) short v8s;
typedef __attribute__((ext_vector_type(4))) float v4f;
typedef __attribute__((ext_vector_type(4))) unsigned int v4u;

__device__ __forceinline__ unsigned short f2bf_rne(float x) {
  unsigned int b = __builtin_bit_cast(unsigned int, x);
  unsigned int r = b + 0x7FFFu + ((b >> 16) & 1u);
  return (unsigned short)(r >> 16);
}
__device__ __forceinline__ unsigned cvtpk(float a, float b) {
  unsigned r;
  asm("v_cvt_pk_bf16_f32 %0, %1, %2" : "=v"(r) : "v"(a), "v"(b));
  return r;
}
__device__ __forceinline__ float bflo(unsigned u) {
  return __builtin_bit_cast(float, u << 16);
}
__device__ __forceinline__ float bfhi(unsigned u) {
  return __builtin_bit_cast(float, u & 0xFFFF0000u);
}

/* ---------- kernel 1: Gamma (f32, [src][dst]) + u0 + emission consts ---------- */
__global__ void build_params(const float* __restrict__ tl,
                             const float* __restrict__ il,
                             const float* __restrict__ ls,
                             float* __restrict__ Gf,
                             float* __restrict__ u0,
                             float* __restrict__ isb,
                             float* __restrict__ cstb) {
  __shared__ float red[MST];
  const int j = threadIdx.x;
  const int b = blockIdx.x;
  float lg;
  if (b < MST) lg = (j == b) ? 0.0f : tl[b * (MST - 1) + (j > b ? j - 1 : j)];
  else         lg = il[j];
  float e = __expf(lg);
  red[j] = e;
  __syncthreads();
  for (int s = MST / 2; s > 0; s >>= 1) {
    if (j < s) red[j] += red[j + s];
    __syncthreads();
  }
  float val = e / red[0];
  if (b < MST) {
    Gf[b * MST + j] = val;
  } else {
    u0[j] = val;
    float c = -((float)DOBS * 0.5f) * LOG2PI_F;
#pragma unroll
    for (int d = 0; d < DOBS; ++d) {
      float l = ls[j * DOBS + d];
      isb[j * DOBS + d] = __expf(-l);
      c -= l;
    }
    cstb[j] = c;
  }
}

/* ---------- kernel 1b: permuted Gamma^T A-fragments (bf16 RNE) ---------- */
__global__ void build_afrag(const float* __restrict__ Gf,
                            unsigned short* __restrict__ GA) {
  const int idx = blockIdx.x * 64 + threadIdx.x;  /* (m*4+kt)*64 + l */
  const int l  = idx & 63;
  const int mk = idx >> 6;
  const int kt = mk & 3, m = mk >> 2;
  const int i  = l & 15, hh = l >> 4;
  const int rg = 16 * m + i;
  const int lam = ((rg >> 5) << 5) | (((rg >> 2) & 3) << 3) | (((rg >> 4) & 1) << 2) | (rg & 3);
  unsigned short o[8];
#pragma unroll
  for (int j = 0; j < 8; ++j) {
    const int src = 32 * kt + 8 * hh + j;
    o[j] = f2bf_rne(Gf[src * MST + lam]);
  }
  *(v4u*)(GA + (size_t)idx * 8) = *(const v4u*)o;
}

/* ---------- kernel 2: emission densities -> bf16 ---------- */
__global__ void emis_kernel(const float* __restrict__ y,
                            const float* __restrict__ mu,
                            const float* __restrict__ isb,
                            const float* __restrict__ cstb,
                            unsigned short* __restrict__ g0) {
  const int j  = threadIdx.x;
  const int tb = blockIdx.x * EROWS;
  __shared__ float ysh[EROWS * DOBS];
  ysh[j] = y[(unsigned)tb * DOBS + j];
  __syncthreads();
  float m[DOBS], is[DOBS];
  float cst = cstb[j];
#pragma unroll
  for (int d = 0; d < DOBS; ++d) { m[d] = mu[j * DOBS + d]; is[d] = isb[j * DOBS + d]; }
#pragma unroll
  for (int r = 0; r < EROWS; ++r) {
    float q = 0.0f;
#pragma unroll
    for (int d = 0; d < DOBS; ++d) {
      float z = (ysh[r * DOBS + d] - m[d]) * is[d];
      q = fmaf(z, z, q);
    }
    g0[(unsigned)(tb + r) * MST + j] = f2bf_rne(__expf(fmaf(-0.5f, q, cst)));
  }
}

/* ---------- scan internals ---------- */
__device__ __forceinline__ void packB(const v4f* w, v8s* Bh, v8s* Bl, bool full) {
#pragma unroll
  for (int kt = 0; kt < 4; ++kt) {
    const v4f wa = w[2 * kt], wb = w[2 * kt + 1];
    const unsigned r0 = cvtpk(wa[0], wa[1]), r1 = cvtpk(wa[2], wa[3]);
    const unsigned r2 = cvtpk(wb[0], wb[1]), r3 = cvtpk(wb[2], wb[3]);
    Bh[kt] = __builtin_bit_cast(v8s, (v4u){r0, r1, r2, r3});
    if (full) {
      const float l0 = wa[0] - bflo(r0);
      const float l1 = wa[1] - bfhi(r0);
      const float l2 = wa[2] - bflo(r1);
      const float l3 = wa[3] - bfhi(r1);
      const float l4 = wb[0] - bflo(r2);
      const float l5 = wb[1] - bfhi(r2);
      const float l6 = wb[2] - bflo(r3);
      const float l7 = wb[3] - bfhi(r3);
      Bl[kt] = __builtin_bit_cast(v8s, (v4u){cvtpk(l0, l1), cvtpk(l2, l3),
                                             cvtpk(l4, l5), cvtpk(l6, l7)});
    }
  }
}

/* one scan step: consumes `cur` (g[tcur] raw bf16) and refills it with g[tcur+3] */
template<bool MF, bool PF, bool LIVE, bool REIN>
__device__ __forceinline__ void step(
    int n, int wid, int c, int h,
    const v8s* A, v8s* Bh, v8s* Bl, v4u (&cur)[4],
    float& inv, unsigned& gvo, unsigned& uvo,
    const char* gbase, const float* u0,
    char* outUt, char* outF, char* outUtt) {
  /* 1. D = W~ @ Gamma_hi (state hi, + state lo if MF) */
  v4f D[8] = {};
#pragma unroll
  for (int kt = 0; kt < 4; ++kt)
#pragma unroll
    for (int m = 0; m < 8; ++m)
      D[m] = __builtin_amdgcn_mfma_f32_16x16x32_bf16(A[m * 4 + kt], Bh[kt], D[m], 0, 0, 0);
  if (MF) {
#pragma unroll
    for (int kt = 0; kt < 4; ++kt)
#pragma unroll
      for (int m = 0; m < 8; ++m)
        D[m] = __builtin_amdgcn_mfma_f32_16x16x32_bf16(A[m * 4 + kt], Bl[kt], D[m], 0, 0, 0);
  }

  /* 2. convert g (bf16->f32) and fold inv_{n-1} */
  v4f gci[8];
#pragma unroll
  for (int mm = 0; mm < 4; ++mm) {
    const v4u raw = cur[mm];
    gci[2 * mm + 0] = (v4f){bflo(raw.x), bfhi(raw.x), bflo(raw.y), bfhi(raw.y)} * inv;
    gci[2 * mm + 1] = (v4f){bflo(raw.z), bfhi(raw.z), bflo(raw.w), bfhi(raw.w)} * inv;
  }

  /* 3. refill cur with g[tcur+3] (3-step latency slack) */
#pragma unroll
  for (int mm = 0; mm < 4; ++mm)
    cur[mm] = *(const v4u*)(gbase + (gvo + (unsigned)mm * 64u));
  gvo += 256u;

  /* 4. predicted dist -> Utt (live) ; w~ = p~ * g */
  if (LIVE) {
#pragma unroll
    for (int m = 0; m < 8; ++m) {
      v4f p = D[m] * inv;
      *(v4f*)(outUtt + (uvo + (m >> 1) * 128 + (m & 1) * 16)) = p;
    }
  }
  v4f w[8];
#pragma unroll
  for (int m = 0; m < 8; ++m) w[m] = D[m] * gci[m];

  /* 5. exact u0 injection for wave-0 early chains (state at t=-1 := u0) */
  if (REIN) {
    if (wid == 0 && ((n & 7) == 7)) {
      const int ctar = (WARM - 1 - n) >> 3;
#pragma unroll
      for (int m = 0; m < 8; ++m) {
        v4f uv = *(const v4f*)(u0 + (m >> 1) * 32 + h * 8 + (m & 1) * 4);
        if (c == ctar) w[m] = uv;
      }
    }
  }

  /* 6. rowsum S = f_t (per chain: over m,q and across h) */
  v4f a0 = w[0] + w[1], a1 = w[2] + w[3], a2 = w[4] + w[5], a3 = w[6] + w[7];
  v4f a6 = (a0 + a1) + (a2 + a3);
  float s = (a6[0] + a6[1]) + (a6[2] + a6[3]);
  s += __shfl_xor(s, 16);
  s += __shfl_xor(s, 32);
  const float invn = __builtin_amdgcn_rcpf(s);

  /* 7. repack state (layout-closed) */
  packB(w, Bh, Bl, PF);

  /* 8. filtered dist + f (live) */
  if (LIVE) {
#pragma unroll
    for (int m = 0; m < 8; ++m) {
      v4f ut = w[m] * invn;
      *(v4f*)(outUt + (uvo + (m >> 1) * 128 + (m & 1) * 16)) = ut;
    }
    if (h == 0) *(float*)(outF + (uvo >> 7)) = s;
  }
  uvo += 512u;
  inv = invn;
}

/* ---------- kernel 3: barrier-free in-register MFMA scan ---------- */
__global__ __launch_bounds__(64, 1)
void hmm_scan(const char* __restrict__ gbase,     /* bf16 rows: g[t] at (t+GPAD)*256 B */
              const unsigned short* __restrict__ GA,
              const float* __restrict__ u0,
              char* __restrict__ outUt,
              char* __restrict__ outF,
              char* __restrict__ outUtt) {
  const int l = threadIdx.x;
  const int h = l >> 4, c = l & 15;
  const int wid = blockIdx.x;
  const int t00 = (wid * 16 + c) * CLEN;
  const int t0  = t00 - WARM;

  /* Gamma^T A-fragments: 32 x v8s = 128 VGPR, loop-invariant */
  v8s A[32];
#pragma unroll
  for (int f = 0; f < 32; ++f)
    A[f] = *(const v8s*)(GA + (size_t)(f * 64 + l) * 8);

  /* initial state: uniform; wave-0 chain WARM/CLEN starts exactly at u0 */
  v4f w[8];
#pragma unroll
  for (int m = 0; m < 8; ++m)
    w[m] = (v4f){1.0f / MST, 1.0f / MST, 1.0f / MST, 1.0f / MST};
  if (wid == 0 && c == (WARM / CLEN)) {
#pragma unroll
    for (int m = 0; m < 8; ++m)
      w[m] = *(const v4f*)(u0 + (m >> 1) * 32 + h * 8 + (m & 1) * 4);
  }
  float inv = 1.0f;

  v8s Bh[4], Bl[4];
  packB(w, Bh, Bl, true);

  /* g pipeline: three raw bf16 row-buffers, refilled in place */
  unsigned gvo = (unsigned)((t0 + GPAD) * 256 + h * 16);
  v4u gA[4], gB[4], gC[4];
#pragma unroll
  for (int mm = 0; mm < 4; ++mm) {
    gA[mm] = *(const v4u*)(gbase + (gvo + (unsigned)mm * 64u));
    gB[mm] = *(const v4u*)(gbase + (gvo + 256u + (unsigned)mm * 64u));
    gC[mm] = *(const v4u*)(gbase + (gvo + 512u + (unsigned)mm * 64u));
  }
  gvo += 768u;                                   /* -> t0+3 */
  unsigned uvo = (unsigned)(t0 * 512 + h * 32);

#define ARGS A, Bh, Bl
#define TAIL inv, gvo, uvo, gbase, u0, outUt, outF, outUtt
  /* phase A: hi-only state, n = 0..29 */
  for (int n = 0; n < 30; n += 3) {
    step<false, false, false, true>(n + 0, wid, c, h, ARGS, gA, TAIL);
    step<false, false, false, true>(n + 1, wid, c, h, ARGS, gB, TAIL);
    step<false, false, false, true>(n + 2, wid, c, h, ARGS, gC, TAIL);
  }
  /* n = 30,31 hi-only; n = 32 hi-only MFMA but FULL pack (transition) */
  step<false, false, false, true>(30, wid, c, h, ARGS, gA, TAIL);
  step<false, false, false, true>(31, wid, c, h, ARGS, gB, TAIL);
  step<false, true,  false, true>(32, wid, c, h, ARGS, gC, TAIL);
  /* phase B: full split, warm, n = 33..47 */
  for (int n = 33; n < 48; n += 3) {
    step<true, true, false, true>(n + 0, wid, c, h, ARGS, gA, TAIL);
    step<true, true, false, true>(n + 1, wid, c, h, ARGS, gB, TAIL);
    step<true, true, false, true>(n + 2, wid, c, h, ARGS, gC, TAIL);
  }
  /* phase C: live, n = 48..55 */
  for (int n = 48; n < 54; n += 3) {
    step<true, true, true, false>(n + 0, wid, c, h, ARGS, gA, TAIL);
    step<true, true, true, false>(n + 1, wid, c, h, ARGS, gB, TAIL);
    step<true, true, true, false>(n + 2, wid, c, h, ARGS, gC, TAIL);
  }
  step<true, true, true, false>(54, wid, c, h, ARGS, gA, TAIL);
  step<true, true, true, false>(55, wid, c, h, ARGS, gB, TAIL);
#undef ARGS
#undef TAIL
}

extern "C" void kernel_launch(void* const* d_in, const int* in_sizes, int n_in,
                              void* d_out, int out_size, void* d_ws, size_t ws_size,
                              hipStream_t stream) {
  const float* y  = (const float*)d_in[0];
  const float* tl = (const float*)d_in[1];
  const float* il = (const float*)d_in[2];
  const float* mu = (const float*)d_in[3];
  const float* ls = (const float*)d_in[4];

  /* ws: bf16 g (padded) | u0 | Gf | GA | isb | cstb  (~34 MB) */
  unsigned short* gf16 = (unsigned short*)d_ws;         /* (GPAD+TLEN+GPAD) x 128 bf16 */
  unsigned short* g0   = gf16 + (size_t)GPAD * MST;
  float* u0 = (float*)(gf16 + (size_t)(TLEN + 2 * GPAD) * MST);
  float* Gf = u0 + MST;
  unsigned short* GA = (unsigned short*)(Gf + MST * MST);
  float* isb  = (float*)(GA + 32 * 64 * 8);
  float* cstb = isb + MST * DOBS;

  char* outUt  = (char*)d_out;
  char* outF   = outUt + (size_t)TLEN * MST * 4;
  char* outUtt = outF + (size_t)TLEN * 4;

  build_params<<<MST + 1, MST, 0, stream>>>(tl, il, ls, Gf, u0, isb, cstb);
  build_afrag<<<32, 64, 0, stream>>>(Gf, GA);
  emis_kernel<<<TLEN / EROWS, MST, 0, stream>>>(y, mu, isb, cstb, g0);
  hmm_scan<<<NW, 64, 0, stream>>>((const char*)gf16, GA, u0, outUt, outF, outUtt);
}

// Round 9
// 90.553 us; speedup vs baseline: 4.0067x; 1.0154x over previous
//
#include <hip/hip_runtime.h>
#include <math.h>

#define MST   128
#define DOBS  8
#define TLEN  131072
#define LOG2PI_F 1.8378770664093453f

#define CLEN  8
#define NW    (TLEN / CLEN / 16)   /* 1024 waves: one per SIMD */
#define WARM  48
#define NSTEP (WARM + CLEN)        /* 56 */
#define GPAD  128
#define EROWS 16

typedef __attribute__((ext_vector_type(8))) short v8s;
typedef __attribute__((ext_vector_type(4))) float v4f;
typedef __attribute__((ext_vector_type(4))) unsigned int v4u;

__device__ __forceinline__ unsigned short f2bf_rne(float x) {
  unsigned int b = __builtin_bit_cast(unsigned int, x);
  unsigned int r = b + 0x7FFFu + ((b >> 16) & 1u);
  return (unsigned short)(r >> 16);
}
__device__ __forceinline__ unsigned cvtpk(float a, float b) {
  unsigned r;
  asm("v_cvt_pk_bf16_f32 %0, %1, %2" : "=v"(r) : "v"(a), "v"(b));
  return r;
}
__device__ __forceinline__ float bflo(unsigned u) {
  return __builtin_bit_cast(float, u << 16);
}
__device__ __forceinline__ float bfhi(unsigned u) {
  return __builtin_bit_cast(float, u & 0xFFFF0000u);
}

/* ---------- kernel 1: Gamma (f32, [src][dst]) + u0 + emission consts ---------- */
__global__ void build_params(const float* __restrict__ tl,
                             const float* __restrict__ il,
                             const float* __restrict__ ls,
                             float* __restrict__ Gf,
                             float* __restrict__ u0,
                             float* __restrict__ isb,
                             float* __restrict__ cstb) {
  __shared__ float red[MST];
  const int j = threadIdx.x;
  const int b = blockIdx.x;
  float lg;
  if (b < MST) lg = (j == b) ? 0.0f : tl[b * (MST - 1) + (j > b ? j - 1 : j)];
  else         lg = il[j];
  float e = __expf(lg);
  red[j] = e;
  __syncthreads();
  for (int s = MST / 2; s > 0; s >>= 1) {
    if (j < s) red[j] += red[j + s];
    __syncthreads();
  }
  float val = e / red[0];
  if (b < MST) {
    Gf[b * MST + j] = val;
  } else {
    u0[j] = val;
    float c = -((float)DOBS * 0.5f) * LOG2PI_F;
#pragma unroll
    for (int d = 0; d < DOBS; ++d) {
      float l = ls[j * DOBS + d];
      isb[j * DOBS + d] = __expf(-l);
      c -= l;
    }
    cstb[j] = c;
  }
}

/* ---------- kernel 1b: permuted Gamma^T A-fragments (bf16 RNE) ---------- */
__global__ void build_afrag(const float* __restrict__ Gf,
                            unsigned short* __restrict__ GA) {
  const int idx = blockIdx.x * 64 + threadIdx.x;  /* (m*4+kt)*64 + l */
  const int l  = idx & 63;
  const int mk = idx >> 6;
  const int kt = mk & 3, m = mk >> 2;
  const int i  = l & 15, hh = l >> 4;
  const int rg = 16 * m + i;
  const int lam = ((rg >> 5) << 5) | (((rg >> 2) & 3) << 3) | (((rg >> 4) & 1) << 2) | (rg & 3);
  unsigned short o[8];
#pragma unroll
  for (int j = 0; j < 8; ++j) {
    const int src = 32 * kt + 8 * hh + j;
    o[j] = f2bf_rne(Gf[src * MST + lam]);
  }
  *(v4u*)(GA + (size_t)idx * 8) = *(const v4u*)o;
}

/* ---------- kernel 2: emission densities -> bf16 ---------- */
__global__ void emis_kernel(const float* __restrict__ y,
                            const float* __restrict__ mu,
                            const float* __restrict__ isb,
                            const float* __restrict__ cstb,
                            unsigned short* __restrict__ g0) {
  const int j  = threadIdx.x;
  const int tb = blockIdx.x * EROWS;
  __shared__ float ysh[EROWS * DOBS];
  ysh[j] = y[(unsigned)tb * DOBS + j];
  __syncthreads();
  float m[DOBS], is[DOBS];
  float cst = cstb[j];
#pragma unroll
  for (int d = 0; d < DOBS; ++d) { m[d] = mu[j * DOBS + d]; is[d] = isb[j * DOBS + d]; }
#pragma unroll
  for (int r = 0; r < EROWS; ++r) {
    float q = 0.0f;
#pragma unroll
    for (int d = 0; d < DOBS; ++d) {
      float z = (ysh[r * DOBS + d] - m[d]) * is[d];
      q = fmaf(z, z, q);
    }
    g0[(unsigned)(tb + r) * MST + j] = f2bf_rne(__expf(fmaf(-0.5f, q, cst)));
  }
}

/* ---------- scan internals ---------- */
__device__ __forceinline__ void packB(const v4f* w, v8s* Bh, v8s* Bl, bool full) {
#pragma unroll
  for (int kt = 0; kt < 4; ++kt) {
    const v4f wa = w[2 * kt], wb = w[2 * kt + 1];
    const unsigned r0 = cvtpk(wa[0], wa[1]), r1 = cvtpk(wa[2], wa[3]);
    const unsigned r2 = cvtpk(wb[0], wb[1]), r3 = cvtpk(wb[2], wb[3]);
    Bh[kt] = __builtin_bit_cast(v8s, (v4u){r0, r1, r2, r3});
    if (full) {
      const float l0 = wa[0] - bflo(r0);
      const float l1 = wa[1] - bfhi(r0);
      const float l2 = wa[2] - bflo(r1);
      const float l3 = wa[3] - bfhi(r1);
      const float l4 = wb[0] - bflo(r2);
      const float l5 = wb[1] - bfhi(r2);
      const float l6 = wb[2] - bflo(r3);
      const float l7 = wb[3] - bfhi(r3);
      Bl[kt] = __builtin_bit_cast(v8s, (v4u){cvtpk(l0, l1), cvtpk(l2, l3),
                                             cvtpk(l4, l5), cvtpk(l6, l7)});
    }
  }
}

/* one scan step: consumes `cur` (g[tcur] raw bf16) and refills it with g[tcur+3].
   MF: include state-lo MFMA pass; PF: produce full hi/lo pack.
   LP: live/inject checks possible (runtime, wave-uniform n). */
template<bool MF, bool PF, bool LP>
__device__ __forceinline__ void step(
    int n, int wid, int c, int h,
    const v8s* A, v8s* Bh, v8s* Bl, v4u (&cur)[4],
    float& inv, unsigned& gvo, unsigned& uvo,
    const char* gbase, const float* u0,
    char* outUt, char* outF, char* outUtt) {
  const bool live = LP && (n >= WARM);

  /* 1. D = W~ @ Gamma_hi (state hi, + state lo if MF) */
  v4f D[8] = {};
#pragma unroll
  for (int kt = 0; kt < 4; ++kt)
#pragma unroll
    for (int m = 0; m < 8; ++m)
      D[m] = __builtin_amdgcn_mfma_f32_16x16x32_bf16(A[m * 4 + kt], Bh[kt], D[m], 0, 0, 0);
  if (MF) {
#pragma unroll
    for (int kt = 0; kt < 4; ++kt)
#pragma unroll
      for (int m = 0; m < 8; ++m)
        D[m] = __builtin_amdgcn_mfma_f32_16x16x32_bf16(A[m * 4 + kt], Bl[kt], D[m], 0, 0, 0);
  }

  /* 2. convert g (bf16->f32) and fold inv_{n-1} */
  v4f gci[8];
#pragma unroll
  for (int mm = 0; mm < 4; ++mm) {
    const v4u raw = cur[mm];
    gci[2 * mm + 0] = (v4f){bflo(raw.x), bfhi(raw.x), bflo(raw.y), bfhi(raw.y)} * inv;
    gci[2 * mm + 1] = (v4f){bflo(raw.z), bfhi(raw.z), bflo(raw.w), bfhi(raw.w)} * inv;
  }

  /* 3. refill cur with g[tcur+3] (3-step latency slack) */
#pragma unroll
  for (int mm = 0; mm < 4; ++mm)
    cur[mm] = *(const v4u*)(gbase + (gvo + (unsigned)mm * 64u));
  gvo += 256u;

  /* 4. predicted dist -> Utt (live); w~ = p~ * g */
  if (live) {
#pragma unroll
    for (int m = 0; m < 8; ++m) {
      v4f p = D[m] * inv;
      *(v4f*)(outUtt + (uvo + (m >> 1) * 128 + (m & 1) * 16)) = p;
    }
  }
  v4f w[8];
#pragma unroll
  for (int m = 0; m < 8; ++m) w[m] = D[m] * gci[m];

  /* 5. exact u0 injection for wave-0 early chains (state at t=-1 := u0) */
  if (LP) {
    if (wid == 0 && n < WARM && ((n & 7) == 7)) {
      const int ctar = (WARM - 1 - n) >> 3;
#pragma unroll
      for (int m = 0; m < 8; ++m) {
        v4f uv = *(const v4f*)(u0 + (m >> 1) * 32 + h * 8 + (m & 1) * 4);
        if (c == ctar) w[m] = uv;
      }
    }
  }

  /* 6. rowsum S = f_t (off critical path: inv used only after next MFMAs) */
  v4f a0 = w[0] + w[1], a1 = w[2] + w[3], a2 = w[4] + w[5], a3 = w[6] + w[7];
  v4f a6 = (a0 + a1) + (a2 + a3);
  float s = (a6[0] + a6[1]) + (a6[2] + a6[3]);
  s += __shfl_xor(s, 16);
  s += __shfl_xor(s, 32);
  const float invn = __builtin_amdgcn_rcpf(s);

  /* 7. repack state (layout-closed: no cross-lane moves) */
  packB(w, Bh, Bl, PF);

  /* 8. filtered dist + f (live) */
  if (live) {
#pragma unroll
    for (int m = 0; m < 8; ++m) {
      v4f ut = w[m] * invn;
      *(v4f*)(outUt + (uvo + (m >> 1) * 128 + (m & 1) * 16)) = ut;
    }
    if (h == 0) *(float*)(outF + (uvo >> 7)) = s;
  }
  uvo += 512u;
  inv = invn;
}

/* ---------- kernel 3: barrier-free in-register MFMA scan, I$-resident rolled loops ---------- */
__global__ __launch_bounds__(64, 1)
void hmm_scan(const char* __restrict__ gbase,     /* bf16 rows: g[t] at (t+GPAD)*256 B */
              const unsigned short* __restrict__ GA,
              const float* __restrict__ u0,
              char* __restrict__ outUt,
              char* __restrict__ outF,
              char* __restrict__ outUtt) {
  const int l = threadIdx.x;
  const int h = l >> 4, c = l & 15;
  const int wid = blockIdx.x;
  const int t00 = (wid * 16 + c) * CLEN;
  const int t0  = t00 - WARM;

  /* Gamma^T A-fragments: 32 x v8s = 128 VGPR, loop-invariant */
  v8s A[32];
#pragma unroll
  for (int f = 0; f < 32; ++f)
    A[f] = *(const v8s*)(GA + (size_t)(f * 64 + l) * 8);

  /* initial state: uniform; wave-0 chain WARM/CLEN starts exactly at u0 */
  v4f w[8];
#pragma unroll
  for (int m = 0; m < 8; ++m)
    w[m] = (v4f){1.0f / MST, 1.0f / MST, 1.0f / MST, 1.0f / MST};
  if (wid == 0 && c == (WARM / CLEN)) {
#pragma unroll
    for (int m = 0; m < 8; ++m)
      w[m] = *(const v4f*)(u0 + (m >> 1) * 32 + h * 8 + (m & 1) * 4);
  }
  float inv = 1.0f;

  v8s Bh[4], Bl[4];
  packB(w, Bh, Bl, true);

  /* g pipeline: three raw bf16 row-buffers, refilled in place; buffer = n mod 3 */
  unsigned gvo = (unsigned)((t0 + GPAD) * 256 + h * 16);
  v4u gA[4], gB[4], gC[4];
#pragma unroll
  for (int mm = 0; mm < 4; ++mm) {
    gA[mm] = *(const v4u*)(gbase + (gvo + (unsigned)mm * 64u));
    gB[mm] = *(const v4u*)(gbase + (gvo + 256u + (unsigned)mm * 64u));
    gC[mm] = *(const v4u*)(gbase + (gvo + 512u + (unsigned)mm * 64u));
  }
  gvo += 768u;                                   /* -> t0+3 */
  unsigned uvo = (unsigned)(t0 * 512 + h * 32);

#define SARG wid, c, h, A, Bh, Bl
#define TAIL inv, gvo, uvo, gbase, u0, outUt, outF, outUtt
  /* phase A: hi-only state, rolled (13 iters x 3 steps), n = 0..38 */
#pragma clang loop unroll(disable)
  for (int n = 0; n < 39; n += 3) {
    step<false, false, true>(n + 0, SARG, gA, TAIL);
    step<false, false, true>(n + 1, SARG, gB, TAIL);
    step<false, false, true>(n + 2, SARG, gC, TAIL);
  }
  /* transition: hi-only MFMA, FULL pack */
  step<false, true, true>(39, SARG, gA, TAIL);
  /* phase B/C merged: full split, live when n>=WARM; rolled (5 iters x 3), n = 40..54 */
#pragma clang loop unroll(disable)
  for (int n = 40; n < 55; n += 3) {
    step<true, true, true>(n + 0, SARG, gB, TAIL);
    step<true, true, true>(n + 1, SARG, gC, TAIL);
    step<true, true, true>(n + 2, SARG, gA, TAIL);
  }
  step<true, true, true>(55, SARG, gB, TAIL);
#undef SARG
#undef TAIL
}

extern "C" void kernel_launch(void* const* d_in, const int* in_sizes, int n_in,
                              void* d_out, int out_size, void* d_ws, size_t ws_size,
                              hipStream_t stream) {
  const float* y  = (const float*)d_in[0];
  const float* tl = (const float*)d_in[1];
  const float* il = (const float*)d_in[2];
  const float* mu = (const float*)d_in[3];
  const float* ls = (const float*)d_in[4];

  /* ws: bf16 g (padded) | u0 | Gf | GA | isb | cstb  (~34 MB) */
  unsigned short* gf16 = (unsigned short*)d_ws;         /* (GPAD+TLEN+GPAD) x 128 bf16 */
  unsigned short* g0   = gf16 + (size_t)GPAD * MST;
  float* u0 = (float*)(gf16 + (size_t)(TLEN + 2 * GPAD) * MST);
  float* Gf = u0 + MST;
  unsigned short* GA = (unsigned short*)(Gf + MST * MST);
  float* isb  = (float*)(GA + 32 * 64 * 8);
  float* cstb = isb + MST * DOBS;

  char* outUt  = (char*)d_out;
  char* outF   = outUt + (size_t)TLEN * MST * 4;
  char* outUtt = outF + (size_t)TLEN * 4;

  build_params<<<MST + 1, MST, 0, stream>>>(tl, il, ls, Gf, u0, isb, cstb);
  build_afrag<<<32, 64, 0, stream>>>(Gf, GA);
  emis_kernel<<<TLEN / EROWS, MST, 0, stream>>>(y, mu, isb, cstb, g0);
  hmm_scan<<<NW, 64, 0, stream>>>((const char*)gf16, GA, u0, outUt, outF, outUtt);
}